// Round 1
// baseline (2836.182 us; speedup 1.0000x reference)
//
#include <hip/hip_runtime.h>
#include <cstdint>
#include <cstddef>

#define L_SEQ   2048
#define DMODEL  1024
#define DINNER  2048
#define NHEADS_ 32
#define HEADDIM_ 64
#define DSTATE  64
#define CONVDIM 2304
#define DINPROJ 4416
#define BATCH_  2
#define EPS_    1e-5f

__device__ __forceinline__ float silu_f(float v) { return v / (1.f + __expf(-v)); }

// ---------------- GEMM: C[M][N] = A[M][K] * B[N][K]^T  (both row-major, "NT") ----------
template<int BM, int BN, int BK>
__global__ __launch_bounds__(256)
void gemm_nt(const float* __restrict__ A, const float* __restrict__ B,
             float* __restrict__ C, int M, int N, int K) {
    __shared__ __align__(16) float As[BK][BM + 4];
    __shared__ __align__(16) float Bs[BK][BN + 4];
    const int tid = threadIdx.x;
    const int bm = blockIdx.y * BM;
    const int bn = blockIdx.x * BN;
    const int tx = tid & 15;        // 0..15 -> N
    const int ty = tid >> 4;        // 0..15 -> M
    const int sr = tid >> 2;        // 0..63 staging row
    const int skq = tid & 3;        // quad-of-4 floats along K

    float acc[4][4];
#pragma unroll
    for (int m = 0; m < 4; ++m)
#pragma unroll
        for (int n = 0; n < 4; ++n) acc[m][n] = 0.f;

    for (int k0 = 0; k0 < K; k0 += BK) {
        float4 av = *reinterpret_cast<const float4*>(&A[(size_t)(bm + sr) * K + k0 + skq * 4]);
        float4 bv = *reinterpret_cast<const float4*>(&B[(size_t)(bn + sr) * K + k0 + skq * 4]);
        __syncthreads();   // previous iteration's readers done
        As[skq * 4 + 0][sr] = av.x; As[skq * 4 + 1][sr] = av.y;
        As[skq * 4 + 2][sr] = av.z; As[skq * 4 + 3][sr] = av.w;
        Bs[skq * 4 + 0][sr] = bv.x; Bs[skq * 4 + 1][sr] = bv.y;
        Bs[skq * 4 + 2][sr] = bv.z; Bs[skq * 4 + 3][sr] = bv.w;
        __syncthreads();
#pragma unroll
        for (int kk = 0; kk < BK; ++kk) {
            float4 a4 = *reinterpret_cast<const float4*>(&As[kk][ty * 4]);
            float4 b4 = *reinterpret_cast<const float4*>(&Bs[kk][tx * 4]);
            float am[4] = {a4.x, a4.y, a4.z, a4.w};
            float bn_[4] = {b4.x, b4.y, b4.z, b4.w};
#pragma unroll
            for (int m = 0; m < 4; ++m)
#pragma unroll
                for (int n = 0; n < 4; ++n) acc[m][n] += am[m] * bn_[n];
        }
    }
#pragma unroll
    for (int m = 0; m < 4; ++m)
#pragma unroll
        for (int n = 0; n < 4; ++n)
            C[(size_t)(bm + ty * 4 + m) * N + bn + tx * 4 + n] = acc[m][n];
}

// ---------------- depthwise conv (k=7, pad 3) + bias + SiLU --------------------------
__global__ __launch_bounds__(256)
void conv_kernel(const float* __restrict__ zxbcdt, const float* __restrict__ conv_w,
                 const float* __restrict__ conv_b, float* __restrict__ xBCc) {
    const int c = blockIdx.x * 256 + threadIdx.x;   // channel 0..2303
    const int t0 = blockIdx.y * 16;
    const int beta = blockIdx.z;
    float w[7];
#pragma unroll
    for (int k = 0; k < 7; ++k) w[k] = conv_w[c * 7 + k];
    const float bias = conv_b[c];
    const float* in = zxbcdt + (size_t)beta * L_SEQ * DINPROJ + DINNER + c;
    float* outp = xBCc + (size_t)beta * L_SEQ * CONVDIM + c;
    float win[7];
#pragma unroll
    for (int j = 0; j < 6; ++j) {
        int t = t0 - 3 + j;
        win[j] = (t >= 0 && t < L_SEQ) ? in[(size_t)t * DINPROJ] : 0.f;
    }
    for (int i = 0; i < 16; ++i) {
        int t = t0 + i;
        int tl = t + 3;
        win[6] = (tl < L_SEQ) ? in[(size_t)tl * DINPROJ] : 0.f;
        float acc = bias;
#pragma unroll
        for (int k = 0; k < 7; ++k) acc += win[k] * w[k];
        outp[(size_t)t * CONVDIM] = silu_f(acc);
#pragma unroll
        for (int j = 0; j < 6; ++j) win[j] = win[j + 1];
    }
}

// ---------------- sequential selective scan ------------------------------------------
// block = (bd = dir*2+beta in grid.y, head in grid.x); 256 threads:
//   hd = tid>>2 (0..63), dsq = tid&3 -> 16 dstate elems each.
__global__ __launch_bounds__(256)
void scan_kernel(const float* __restrict__ xBCc, const float* __restrict__ zxbcdt,
                 const float* __restrict__ dt_bias, const float* __restrict__ A_log,
                 float* __restrict__ yfw, float* __restrict__ ybw) {
    const int h = blockIdx.x;
    const int bd = blockIdx.y;
    const int dir = bd >> 1, beta = bd & 1;
    const int tid = threadIdx.x;
    const int hd = tid >> 2;
    const int dsq = tid & 3;
    const float Ah = -expf(A_log[h]);
    const float bias = dt_bias[h];

    float state[16];
#pragma unroll
    for (int j = 0; j < 16; ++j) state[j] = 0.f;

    __shared__ float sbuf[2][194];   // [0..63]=x, [64..127]=B, [128..191]=C, [192]=dt_raw
    float* yout = dir ? ybw : yfw;

    // issue loads for step tau; returns the value this thread is responsible for
    auto issue = [&](int tau) -> float {
        const int tt = dir ? (L_SEQ - 1 - tau) : tau;
        const float* xrow = xBCc + ((size_t)beta * L_SEQ + tt) * CONVDIM;
        if (tid < 64)        return xrow[h * 64 + tid];
        else if (tid < 128)  return xrow[DINNER + dir * 128 + (tid - 64)];
        else if (tid < 192)  return xrow[DINNER + dir * 128 + 64 + (tid - 128)];
        else if (tid == 192) return zxbcdt[((size_t)beta * L_SEQ + tt) * DINPROJ + DINNER + CONVDIM + dir * NHEADS_ + h];
        return 0.f;
    };

    float rv = issue(0);
    if (tid < 193) sbuf[0][tid] = rv;
    __syncthreads();

    for (int tau = 0; tau < L_SEQ; ++tau) {
        const int cur = tau & 1;
        float rnext = 0.f;
        if (tau + 1 < L_SEQ) rnext = issue(tau + 1);   // prefetch next step

        const float dtraw = sbuf[cur][192];
        float dtv = dtraw + bias;
        float dts = (dtv > 20.f) ? dtv : log1pf(expf(dtv));
        float ex = expf(Ah * dts);
        float xv = sbuf[cur][hd];
        float cp = 0.f;
#pragma unroll
        for (int j = 0; j < 16; ++j) {
            int ds = dsq * 16 + j;
            state[j] = state[j] * ex + xv * sbuf[cur][64 + ds];
            cp += state[j] * sbuf[cur][128 + ds];
        }
        cp += __shfl_xor(cp, 1);
        cp += __shfl_xor(cp, 2);

        if (dsq == 0) {
            int tout; float val = cp;
            if (dir == 0) {
                tout = tau + 1;
                if (tau == L_SEQ - 1) { tout = 0; val = 0.f; }       // shifted-in zero row
            } else {
                tout = L_SEQ - 2 - tau;
                if (tau == L_SEQ - 1) { tout = L_SEQ - 1; val = 0.f; }
            }
            yout[((size_t)beta * L_SEQ + tout) * DINNER + h * 64 + hd] = val;
        }

        if (tid < 193) sbuf[cur ^ 1][tid] = rnext;
        __syncthreads();   // next buffer visible; also orders reads of sbuf[cur] before overwrite
    }
}

// ---------------- diag_heads = x . fc_D_w^T + Dp  (one wave per row) ------------------
__global__ __launch_bounds__(64)
void diag_kernel(const float* __restrict__ xBCc, const float* __restrict__ fcD,
                 const float* __restrict__ Dp, float* __restrict__ diag) {
    const int row = blockIdx.x;            // beta*L + t
    const int lane = threadIdx.x;
    const float* x = xBCc + (size_t)row * CONVDIM;   // channels 0..2047 = x_og
    float acc[NHEADS_];
#pragma unroll
    for (int hh = 0; hh < NHEADS_; ++hh) acc[hh] = 0.f;
    for (int k0 = 0; k0 < DINNER; k0 += 64) {
        float xv = x[k0 + lane];
#pragma unroll 8
        for (int hh = 0; hh < NHEADS_; ++hh)
            acc[hh] += xv * fcD[(size_t)hh * DINNER + k0 + lane];
    }
#pragma unroll
    for (int hh = 0; hh < NHEADS_; ++hh) {
        float v = acc[hh];
        v += __shfl_xor(v, 1);  v += __shfl_xor(v, 2);  v += __shfl_xor(v, 4);
        v += __shfl_xor(v, 8);  v += __shfl_xor(v, 16); v += __shfl_xor(v, 32);
        acc[hh] = v;
    }
    float outv = 0.f;
#pragma unroll
    for (int hh = 0; hh < NHEADS_; ++hh)
        if (lane == hh) outv = acc[hh];
    if (lane < NHEADS_) diag[(size_t)row * NHEADS_ + lane] = outv + Dp[lane];
}

// ---------------- combine + RMSNorm + silu(z) gate ------------------------------------
__global__ __launch_bounds__(256)
void combine_rms(const float* __restrict__ yfw, const float* __restrict__ ybw,
                 const float* __restrict__ xBCc, const float* __restrict__ diag,
                 const float* __restrict__ zxbcdt, const float* __restrict__ norm_w,
                 float* __restrict__ yout) {
    const int row = blockIdx.x;
    const int tid = threadIdx.x;
    const float* yfr = yfw + (size_t)row * DINNER;
    const float* ybr = ybw + (size_t)row * DINNER;
    const float* xr  = xBCc + (size_t)row * CONVDIM;
    const float* dg  = diag + (size_t)row * NHEADS_;
    const float* zr  = zxbcdt + (size_t)row * DINPROJ;   // channels 0..2047 = z
    float v[8];
    float ss = 0.f;
#pragma unroll
    for (int i = 0; i < 8; ++i) {
        int c = tid * 8 + i;
        float val = yfr[c] + ybr[c] + xr[c] * dg[c >> 6];
        v[i] = val;
        ss += val * val;
    }
    ss += __shfl_xor(ss, 1);  ss += __shfl_xor(ss, 2);  ss += __shfl_xor(ss, 4);
    ss += __shfl_xor(ss, 8);  ss += __shfl_xor(ss, 16); ss += __shfl_xor(ss, 32);
    __shared__ float wsum[4];
    if ((tid & 63) == 0) wsum[tid >> 6] = ss;
    __syncthreads();
    ss = wsum[0] + wsum[1] + wsum[2] + wsum[3];
    const float inv = rsqrtf(ss * (1.f / DINNER) + EPS_);
#pragma unroll
    for (int i = 0; i < 8; ++i) {
        int c = tid * 8 + i;
        float z = zr[c];
        yout[(size_t)row * DINNER + c] = norm_w[c] * v[i] * inv * silu_f(z);
    }
}

extern "C" void kernel_launch(void* const* d_in, const int* in_sizes, int n_in,
                              void* d_out, int out_size, void* d_ws, size_t ws_size,
                              hipStream_t stream) {
    const float* u       = (const float*)d_in[0];
    const float* W_in    = (const float*)d_in[1];
    const float* conv_w  = (const float*)d_in[2];
    const float* conv_b  = (const float*)d_in[3];
    const float* dt_bias = (const float*)d_in[4];
    const float* A_log   = (const float*)d_in[5];
    const float* Dp      = (const float*)d_in[6];
    const float* fc_D_w  = (const float*)d_in[7];
    const float* norm_w  = (const float*)d_in[8];
    const float* W_out   = (const float*)d_in[9];
    float* out = (float*)d_out;

    const int ROWS = BATCH_ * L_SEQ;     // 4096
    float* ws = (float*)d_ws;
    float* zxbcdt = ws;                                    // 4096*4416
    float* xBCc   = zxbcdt + (size_t)ROWS * DINPROJ;       // 4096*2304
    float* yfw    = xBCc   + (size_t)ROWS * CONVDIM;       // 4096*2048
    float* ybw    = yfw    + (size_t)ROWS * DINNER;        // 4096*2048
    float* diag   = ybw    + (size_t)ROWS * DINNER;        // 4096*32

    // 1. in_proj GEMM: zxbcdt = u @ W_in^T   (M=4096, N=4416, K=1024)
    dim3 g1(DINPROJ / 64, ROWS / 64);
    gemm_nt<64, 64, 16><<<g1, 256, 0, stream>>>(u, W_in, zxbcdt, ROWS, DINPROJ, DMODEL);

    // 2. depthwise conv + SiLU
    dim3 gc(CONVDIM / 256, L_SEQ / 16, BATCH_);
    conv_kernel<<<gc, 256, 0, stream>>>(zxbcdt, conv_w, conv_b, xBCc);

    // 3. bidirectional selective scan (includes output shift + reversal)
    dim3 gs(NHEADS_, 4);
    scan_kernel<<<gs, 256, 0, stream>>>(xBCc, zxbcdt, dt_bias, A_log, yfw, ybw);

    // 4. diag heads
    diag_kernel<<<ROWS, 64, 0, stream>>>(xBCc, fc_D_w, Dp, diag);

    // 5. combine + RMS norm + gate (in-place over yfw)
    combine_rms<<<ROWS, 256, 0, stream>>>(yfw, ybw, xBCc, diag, zxbcdt, norm_w, yfw);

    // 6. out_proj GEMM: out = y @ W_out^T   (M=4096, N=1024, K=2048)
    dim3 g3(DMODEL / 64, ROWS / 64);
    gemm_nt<64, 64, 16><<<g3, 256, 0, stream>>>(yfw, W_out, out, ROWS, DMODEL, DINNER);
}

// Round 2
// 2044.798 us; speedup vs baseline: 1.3870x; 1.3870x over previous
//
#include <hip/hip_runtime.h>
#include <cstdint>
#include <cstddef>

#define L_SEQ   2048
#define DMODEL  1024
#define DINNER  2048
#define NHEADS_ 32
#define HEADDIM_ 64
#define DSTATE  64
#define CONVDIM 2304
#define DINPROJ 4416
#define BATCH_  2
#define EPS_    1e-5f
#define CH      16        // scan chunk (time steps staged per LDS buffer)

__device__ __forceinline__ float silu_f(float v) { return v / (1.f + __expf(-v)); }

// ---------------- GEMM: C[M][N] = A[M][K] * B[N][K]^T  (both row-major, "NT") ----------
template<int BM, int BN, int BK>
__global__ __launch_bounds__(256)
void gemm_nt(const float* __restrict__ A, const float* __restrict__ B,
             float* __restrict__ C, int M, int N, int K) {
    __shared__ __align__(16) float As[BK][BM + 4];
    __shared__ __align__(16) float Bs[BK][BN + 4];
    const int tid = threadIdx.x;
    const int bm = blockIdx.y * BM;
    const int bn = blockIdx.x * BN;
    const int tx = tid & 15;        // 0..15 -> N
    const int ty = tid >> 4;        // 0..15 -> M
    const int sr = tid >> 2;        // 0..63 staging row
    const int skq = tid & 3;        // quad-of-4 floats along K

    float acc[4][4];
#pragma unroll
    for (int m = 0; m < 4; ++m)
#pragma unroll
        for (int n = 0; n < 4; ++n) acc[m][n] = 0.f;

    for (int k0 = 0; k0 < K; k0 += BK) {
        float4 av = *reinterpret_cast<const float4*>(&A[(size_t)(bm + sr) * K + k0 + skq * 4]);
        float4 bv = *reinterpret_cast<const float4*>(&B[(size_t)(bn + sr) * K + k0 + skq * 4]);
        __syncthreads();   // previous iteration's readers done
        As[skq * 4 + 0][sr] = av.x; As[skq * 4 + 1][sr] = av.y;
        As[skq * 4 + 2][sr] = av.z; As[skq * 4 + 3][sr] = av.w;
        Bs[skq * 4 + 0][sr] = bv.x; Bs[skq * 4 + 1][sr] = bv.y;
        Bs[skq * 4 + 2][sr] = bv.z; Bs[skq * 4 + 3][sr] = bv.w;
        __syncthreads();
#pragma unroll
        for (int kk = 0; kk < BK; ++kk) {
            float4 a4 = *reinterpret_cast<const float4*>(&As[kk][ty * 4]);
            float4 b4 = *reinterpret_cast<const float4*>(&Bs[kk][tx * 4]);
            float am[4] = {a4.x, a4.y, a4.z, a4.w};
            float bn_[4] = {b4.x, b4.y, b4.z, b4.w};
#pragma unroll
            for (int m = 0; m < 4; ++m)
#pragma unroll
                for (int n = 0; n < 4; ++n) acc[m][n] += am[m] * bn_[n];
        }
    }
#pragma unroll
    for (int m = 0; m < 4; ++m)
#pragma unroll
        for (int n = 0; n < 4; ++n)
            C[(size_t)(bm + ty * 4 + m) * N + bn + tx * 4 + n] = acc[m][n];
}

// ---------------- depthwise conv (k=7, pad 3) + bias + SiLU --------------------------
__global__ __launch_bounds__(256)
void conv_kernel(const float* __restrict__ zxbcdt, const float* __restrict__ conv_w,
                 const float* __restrict__ conv_b, float* __restrict__ xBCc) {
    const int c = blockIdx.x * 256 + threadIdx.x;   // channel 0..2303
    const int t0 = blockIdx.y * 16;
    const int beta = blockIdx.z;
    float w[7];
#pragma unroll
    for (int k = 0; k < 7; ++k) w[k] = conv_w[c * 7 + k];
    const float bias = conv_b[c];
    const float* in = zxbcdt + (size_t)beta * L_SEQ * DINPROJ + DINNER + c;
    float* outp = xBCc + (size_t)beta * L_SEQ * CONVDIM + c;
    float win[7];
#pragma unroll
    for (int j = 0; j < 6; ++j) {
        int t = t0 - 3 + j;
        win[j] = (t >= 0 && t < L_SEQ) ? in[(size_t)t * DINPROJ] : 0.f;
    }
    for (int i = 0; i < 16; ++i) {
        int t = t0 + i;
        int tl = t + 3;
        win[6] = (tl < L_SEQ) ? in[(size_t)tl * DINPROJ] : 0.f;
        float acc = bias;
#pragma unroll
        for (int k = 0; k < 7; ++k) acc += win[k] * w[k];
        outp[(size_t)t * CONVDIM] = silu_f(acc);
#pragma unroll
        for (int j = 0; j < 6; ++j) win[j] = win[j + 1];
    }
}

// ---------------- sequential selective scan, chunked LDS staging ----------------------
// grid = (head 0..31, bd 0..3, half 0..1); 256 threads.
// Per block: 32 hd rows (half of HEADDIM) x 64 dstate -> thread (hd=tid>>3, dsq=tid&7)
// holds 8 state elems. Time chunked by CH=16 rows, double-buffered in LDS; global
// loads for chunk ck+1 are issued into registers BEFORE computing chunk ck (latency
// hides under compute), written to the other LDS buffer after, one barrier per chunk.
__global__ __launch_bounds__(256)
void scan_kernel(const float* __restrict__ xBCc, const float* __restrict__ zxbcdt,
                 const float* __restrict__ dt_bias, const float* __restrict__ A_log,
                 float* __restrict__ yfw, float* __restrict__ ybw) {
    const int h = blockIdx.x;
    const int bd = blockIdx.y;
    const int half = blockIdx.z;
    const int dir = bd >> 1, beta = bd & 1;
    const int tid = threadIdx.x;
    const int hd = tid >> 3;        // 0..31 (local head-dim row)
    const int dsq = tid & 7;        // 8 dstate elems each
    const float Ah = -expf(A_log[h]);
    const float bias = dt_bias[h];

    float state[8];
#pragma unroll
    for (int j = 0; j < 8; ++j) state[j] = 0.f;

    // row layout: [0..31]=x(half), [32..95]=B, [96..159]=C, [160]=dt_raw
    __shared__ float sbuf[2][CH][164];
    float* yout = dir ? ybw : yfw;

    // per-thread staging source (one element per time row)
    const float* src = nullptr;
    size_t stride = 0;
    if (tid < 160) {
        int col = (tid < 32) ? (h * 64 + half * 32 + tid)
                             : (DINNER + dir * 128 + (tid - 32));
        src = xBCc + (size_t)beta * L_SEQ * CONVDIM + col;
        stride = CONVDIM;
    } else if (tid == 160) {
        src = zxbcdt + (size_t)beta * L_SEQ * DINPROJ + DINNER + CONVDIM + dir * NHEADS_ + h;
        stride = DINPROJ;
    }

    float vals[CH];
    auto issue_chunk = [&](int ck) {
        if (src) {
#pragma unroll
            for (int r = 0; r < CH; ++r) {
                int tau = ck * CH + r;
                int tt = dir ? (L_SEQ - 1 - tau) : tau;
                vals[r] = src[(size_t)tt * stride];
            }
        }
    };

    issue_chunk(0);
#pragma unroll
    for (int r = 0; r < CH; ++r)
        if (tid < 161) sbuf[0][r][tid] = vals[r];
    __syncthreads();

    const int NCK = L_SEQ / CH;
    for (int ck = 0; ck < NCK; ++ck) {
        const int cb = ck & 1;
        if (ck + 1 < NCK) issue_chunk(ck + 1);   // overlap with compute below

#pragma unroll
        for (int r = 0; r < CH; ++r) {
            const float dtraw = sbuf[cb][r][160];
            float dtv = dtraw + bias;
            float dts = (dtv > 15.f) ? dtv : log1pf(__expf(dtv));
            float ex = __expf(Ah * dts);
            float xv = sbuf[cb][r][hd];
            const float* Bp = &sbuf[cb][r][32 + dsq * 8];
            const float* Cp = &sbuf[cb][r][96 + dsq * 8];
            float cp = 0.f;
#pragma unroll
            for (int j = 0; j < 8; ++j) {
                state[j] = state[j] * ex + xv * Bp[j];
                cp += state[j] * Cp[j];
            }
            cp += __shfl_xor(cp, 1);
            cp += __shfl_xor(cp, 2);
            cp += __shfl_xor(cp, 4);

            if (dsq == 0) {
                int tau = ck * CH + r;
                int tout; float val = cp;
                if (dir == 0) {
                    tout = tau + 1;
                    if (tau == L_SEQ - 1) { tout = 0; val = 0.f; }
                } else {
                    tout = L_SEQ - 2 - tau;
                    if (tau == L_SEQ - 1) { tout = L_SEQ - 1; val = 0.f; }
                }
                yout[((size_t)beta * L_SEQ + tout) * DINNER + h * 64 + half * 32 + hd] = val;
            }
        }

        if (ck + 1 < NCK) {
#pragma unroll
            for (int r = 0; r < CH; ++r)
                if (tid < 161) sbuf[cb ^ 1][r][tid] = vals[r];
        }
        __syncthreads();
    }
}

// ---------------- diag_heads = x . fc_D_w^T + Dp  (one wave per row) ------------------
__global__ __launch_bounds__(64)
void diag_kernel(const float* __restrict__ xBCc, const float* __restrict__ fcD,
                 const float* __restrict__ Dp, float* __restrict__ diag) {
    const int row = blockIdx.x;            // beta*L + t
    const int lane = threadIdx.x;
    const float* x = xBCc + (size_t)row * CONVDIM;   // channels 0..2047 = x_og
    float acc[NHEADS_];
#pragma unroll
    for (int hh = 0; hh < NHEADS_; ++hh) acc[hh] = 0.f;
    for (int k0 = 0; k0 < DINNER; k0 += 64) {
        float xv = x[k0 + lane];
#pragma unroll 8
        for (int hh = 0; hh < NHEADS_; ++hh)
            acc[hh] += xv * fcD[(size_t)hh * DINNER + k0 + lane];
    }
#pragma unroll
    for (int hh = 0; hh < NHEADS_; ++hh) {
        float v = acc[hh];
        v += __shfl_xor(v, 1);  v += __shfl_xor(v, 2);  v += __shfl_xor(v, 4);
        v += __shfl_xor(v, 8);  v += __shfl_xor(v, 16); v += __shfl_xor(v, 32);
        acc[hh] = v;
    }
    float outv = 0.f;
#pragma unroll
    for (int hh = 0; hh < NHEADS_; ++hh)
        if (lane == hh) outv = acc[hh];
    if (lane < NHEADS_) diag[(size_t)row * NHEADS_ + lane] = outv + Dp[lane];
}

// ---------------- combine + RMSNorm + silu(z) gate ------------------------------------
__global__ __launch_bounds__(256)
void combine_rms(const float* __restrict__ yfw, const float* __restrict__ ybw,
                 const float* __restrict__ xBCc, const float* __restrict__ diag,
                 const float* __restrict__ zxbcdt, const float* __restrict__ norm_w,
                 float* __restrict__ yout) {
    const int row = blockIdx.x;
    const int tid = threadIdx.x;
    const float* yfr = yfw + (size_t)row * DINNER;
    const float* ybr = ybw + (size_t)row * DINNER;
    const float* xr  = xBCc + (size_t)row * CONVDIM;
    const float* dg  = diag + (size_t)row * NHEADS_;
    const float* zr  = zxbcdt + (size_t)row * DINPROJ;   // channels 0..2047 = z
    float v[8];
    float ss = 0.f;
#pragma unroll
    for (int i = 0; i < 8; ++i) {
        int c = tid * 8 + i;
        float val = yfr[c] + ybr[c] + xr[c] * dg[c >> 6];
        v[i] = val;
        ss += val * val;
    }
    ss += __shfl_xor(ss, 1);  ss += __shfl_xor(ss, 2);  ss += __shfl_xor(ss, 4);
    ss += __shfl_xor(ss, 8);  ss += __shfl_xor(ss, 16); ss += __shfl_xor(ss, 32);
    __shared__ float wsum[4];
    if ((tid & 63) == 0) wsum[tid >> 6] = ss;
    __syncthreads();
    ss = wsum[0] + wsum[1] + wsum[2] + wsum[3];
    const float inv = rsqrtf(ss * (1.f / DINNER) + EPS_);
#pragma unroll
    for (int i = 0; i < 8; ++i) {
        int c = tid * 8 + i;
        float z = zr[c];
        yout[(size_t)row * DINNER + c] = norm_w[c] * v[i] * inv * silu_f(z);
    }
}

extern "C" void kernel_launch(void* const* d_in, const int* in_sizes, int n_in,
                              void* d_out, int out_size, void* d_ws, size_t ws_size,
                              hipStream_t stream) {
    const float* u       = (const float*)d_in[0];
    const float* W_in    = (const float*)d_in[1];
    const float* conv_w  = (const float*)d_in[2];
    const float* conv_b  = (const float*)d_in[3];
    const float* dt_bias = (const float*)d_in[4];
    const float* A_log   = (const float*)d_in[5];
    const float* Dp      = (const float*)d_in[6];
    const float* fc_D_w  = (const float*)d_in[7];
    const float* norm_w  = (const float*)d_in[8];
    const float* W_out   = (const float*)d_in[9];
    float* out = (float*)d_out;

    const int ROWS = BATCH_ * L_SEQ;     // 4096
    float* ws = (float*)d_ws;
    float* zxbcdt = ws;                                    // 4096*4416
    float* xBCc   = zxbcdt + (size_t)ROWS * DINPROJ;       // 4096*2304
    float* yfw    = xBCc   + (size_t)ROWS * CONVDIM;       // 4096*2048
    float* ybw    = yfw    + (size_t)ROWS * DINNER;        // 4096*2048
    float* diag   = ybw    + (size_t)ROWS * DINNER;        // 4096*32

    // 1. in_proj GEMM: zxbcdt = u @ W_in^T   (M=4096, N=4416, K=1024)
    dim3 g1(DINPROJ / 64, ROWS / 64);
    gemm_nt<64, 64, 16><<<g1, 256, 0, stream>>>(u, W_in, zxbcdt, ROWS, DINPROJ, DMODEL);

    // 2. depthwise conv + SiLU
    dim3 gc(CONVDIM / 256, L_SEQ / 16, BATCH_);
    conv_kernel<<<gc, 256, 0, stream>>>(zxbcdt, conv_w, conv_b, xBCc);

    // 3. bidirectional selective scan (includes output shift + reversal)
    dim3 gs(NHEADS_, 4, 2);
    scan_kernel<<<gs, 256, 0, stream>>>(xBCc, zxbcdt, dt_bias, A_log, yfw, ybw);

    // 4. diag heads
    diag_kernel<<<ROWS, 64, 0, stream>>>(xBCc, fc_D_w, Dp, diag);

    // 5. combine + RMS norm + gate (in-place over yfw)
    combine_rms<<<ROWS, 256, 0, stream>>>(yfw, ybw, xBCc, diag, zxbcdt, norm_w, yfw);

    // 6. out_proj GEMM: out = y @ W_out^T   (M=4096, N=1024, K=2048)
    dim3 g3(DMODEL / 64, ROWS / 64);
    gemm_nt<64, 64, 16><<<g3, 256, 0, stream>>>(yfw, W_out, out, ROWS, DMODEL, DINNER);
}

// Round 3
// 1505.070 us; speedup vs baseline: 1.8844x; 1.3586x over previous
//
#include <hip/hip_runtime.h>
#include <cstdint>
#include <cstddef>

#define L_SEQ   2048
#define DMODEL  1024
#define DINNER  2048
#define NHEADS_ 32
#define HEADDIM_ 64
#define DSTATE  64
#define CONVDIM 2304
#define DINPROJ 4416
#define BATCH_  2
#define EPS_    1e-5f
#define CH      16        // scan chunk (time steps staged per LDS buffer)

__device__ __forceinline__ float silu_f(float v) { return v / (1.f + __expf(-v)); }

// ---------------- GEMM: C[M][N] = A[M][K] * B[N][K]^T  (both row-major, "NT") ----------
template<int BM, int BN, int BK>
__global__ __launch_bounds__(256)
void gemm_nt(const float* __restrict__ A, const float* __restrict__ B,
             float* __restrict__ C, int M, int N, int K) {
    __shared__ __align__(16) float As[BK][BM + 4];
    __shared__ __align__(16) float Bs[BK][BN + 4];
    const int tid = threadIdx.x;
    const int bm = blockIdx.y * BM;
    const int bn = blockIdx.x * BN;
    const int tx = tid & 15;        // 0..15 -> N
    const int ty = tid >> 4;        // 0..15 -> M
    const int sr = tid >> 2;        // 0..63 staging row
    const int skq = tid & 3;        // quad-of-4 floats along K

    float acc[4][4];
#pragma unroll
    for (int m = 0; m < 4; ++m)
#pragma unroll
        for (int n = 0; n < 4; ++n) acc[m][n] = 0.f;

    for (int k0 = 0; k0 < K; k0 += BK) {
        float4 av = *reinterpret_cast<const float4*>(&A[(size_t)(bm + sr) * K + k0 + skq * 4]);
        float4 bv = *reinterpret_cast<const float4*>(&B[(size_t)(bn + sr) * K + k0 + skq * 4]);
        __syncthreads();   // previous iteration's readers done
        As[skq * 4 + 0][sr] = av.x; As[skq * 4 + 1][sr] = av.y;
        As[skq * 4 + 2][sr] = av.z; As[skq * 4 + 3][sr] = av.w;
        Bs[skq * 4 + 0][sr] = bv.x; Bs[skq * 4 + 1][sr] = bv.y;
        Bs[skq * 4 + 2][sr] = bv.z; Bs[skq * 4 + 3][sr] = bv.w;
        __syncthreads();
#pragma unroll
        for (int kk = 0; kk < BK; ++kk) {
            float4 a4 = *reinterpret_cast<const float4*>(&As[kk][ty * 4]);
            float4 b4 = *reinterpret_cast<const float4*>(&Bs[kk][tx * 4]);
            float am[4] = {a4.x, a4.y, a4.z, a4.w};
            float bn_[4] = {b4.x, b4.y, b4.z, b4.w};
#pragma unroll
            for (int m = 0; m < 4; ++m)
#pragma unroll
                for (int n = 0; n < 4; ++n) acc[m][n] += am[m] * bn_[n];
        }
    }
#pragma unroll
    for (int m = 0; m < 4; ++m)
#pragma unroll
        for (int n = 0; n < 4; ++n)
            C[(size_t)(bm + ty * 4 + m) * N + bn + tx * 4 + n] = acc[m][n];
}

// ---------------- depthwise conv (k=7, pad 3) + bias + SiLU --------------------------
__global__ __launch_bounds__(256)
void conv_kernel(const float* __restrict__ zxbcdt, const float* __restrict__ conv_w,
                 const float* __restrict__ conv_b, float* __restrict__ xBCc) {
    const int c = blockIdx.x * 256 + threadIdx.x;   // channel 0..2303
    const int t0 = blockIdx.y * 16;
    const int beta = blockIdx.z;
    float w[7];
#pragma unroll
    for (int k = 0; k < 7; ++k) w[k] = conv_w[c * 7 + k];
    const float bias = conv_b[c];
    const float* in = zxbcdt + (size_t)beta * L_SEQ * DINPROJ + DINNER + c;
    float* outp = xBCc + (size_t)beta * L_SEQ * CONVDIM + c;
    float win[7];
#pragma unroll
    for (int j = 0; j < 6; ++j) {
        int t = t0 - 3 + j;
        win[j] = (t >= 0 && t < L_SEQ) ? in[(size_t)t * DINPROJ] : 0.f;
    }
    for (int i = 0; i < 16; ++i) {
        int t = t0 + i;
        int tl = t + 3;
        win[6] = (tl < L_SEQ) ? in[(size_t)tl * DINPROJ] : 0.f;
        float acc = bias;
#pragma unroll
        for (int k = 0; k < 7; ++k) acc += win[k] * w[k];
        outp[(size_t)t * CONVDIM] = silu_f(acc);
#pragma unroll
        for (int j = 0; j < 6; ++j) win[j] = win[j + 1];
    }
}

// ---------------- dt/ex precompute: ex[bd][h][tau] = exp(A_h * softplus(dt_raw+bias)) --
// Direction reversal folded in: tau is scan-order time.
__global__ __launch_bounds__(256)
void dtexp_kernel(const float* __restrict__ zxbcdt, const float* __restrict__ dt_bias,
                  const float* __restrict__ A_log, float* __restrict__ exbuf) {
    const int idx = blockIdx.x * 256 + threadIdx.x;     // 4*2048*32
    const int h   = idx & 31;
    const int tau = (idx >> 5) & (L_SEQ - 1);
    const int bd  = idx >> 16;
    const int dir = bd >> 1, beta = bd & 1;
    const int tt  = dir ? (L_SEQ - 1 - tau) : tau;
    const float dtraw = zxbcdt[((size_t)beta * L_SEQ + tt) * DINPROJ + DINNER + CONVDIM + dir * NHEADS_ + h];
    const float Ah = -__expf(A_log[h]);
    const float dtv = dtraw + dt_bias[h];
    const float sp = (dtv > 15.f) ? dtv : log1pf(__expf(dtv));
    exbuf[((size_t)bd * NHEADS_ + h) * L_SEQ + tau] = __expf(Ah * sp);
}

// ---------------- sequential selective scan, chunked LDS staging ----------------------
// grid = (head 0..31, bd 0..3, quarter 0..3); 256 threads = 16 hd x 16 dsq.
// Thread (hd=tid>>4, dsq=tid&15) holds 4 state elems. Time chunked by CH=16,
// double-buffered LDS, loads for chunk ck+1 issued before computing chunk ck.
__global__ __launch_bounds__(256)
void scan_kernel(const float* __restrict__ xBCc, const float* __restrict__ exbuf,
                 float* __restrict__ yfw, float* __restrict__ ybw) {
    const int h = blockIdx.x;
    const int bd = blockIdx.y;
    const int quarter = blockIdx.z;
    const int dir = bd >> 1, beta = bd & 1;
    const int tid = threadIdx.x;
    const int hd = tid >> 4;        // 0..15 (local head-dim row)
    const int dsq = tid & 15;       // 4 dstate elems each

    float state[4] = {0.f, 0.f, 0.f, 0.f};

    // row layout: [0..15]=x(quarter), [16..79]=B, [80..143]=C
    __shared__ float sbuf[2][CH][144];
    __shared__ float exs[2][CH];
    float* yout = dir ? ybw : yfw;

    const float* src = nullptr;
    if (tid < 144) {
        int col = (tid < 16) ? (h * 64 + quarter * 16 + tid)
                             : (DINNER + dir * 128 + (tid - 16));
        src = xBCc + (size_t)beta * L_SEQ * CONVDIM + col;
    }
    const float* exsrc = exbuf + ((size_t)bd * NHEADS_ + h) * L_SEQ;

    float vals[CH];
    float exv = 0.f;
    auto issue_chunk = [&](int ck) {
        if (tid < 144) {
#pragma unroll
            for (int r = 0; r < CH; ++r) {
                int tau = ck * CH + r;
                int tt = dir ? (L_SEQ - 1 - tau) : tau;
                vals[r] = src[(size_t)tt * CONVDIM];
            }
        } else if (tid < 144 + CH) {
            exv = exsrc[ck * CH + (tid - 144)];
        }
    };

    issue_chunk(0);
    if (tid < 144) {
#pragma unroll
        for (int r = 0; r < CH; ++r) sbuf[0][r][tid] = vals[r];
    } else if (tid < 144 + CH) {
        exs[0][tid - 144] = exv;
    }
    __syncthreads();

    const int NCK = L_SEQ / CH;
    for (int ck = 0; ck < NCK; ++ck) {
        const int cb = ck & 1;
        if (ck + 1 < NCK) issue_chunk(ck + 1);   // overlap with compute below

#pragma unroll
        for (int r = 0; r < CH; ++r) {
            const float ex = exs[cb][r];
            const float xv = sbuf[cb][r][hd];
            const float4 bv = *reinterpret_cast<const float4*>(&sbuf[cb][r][16 + dsq * 4]);
            const float4 cv = *reinterpret_cast<const float4*>(&sbuf[cb][r][80 + dsq * 4]);
            state[0] = state[0] * ex + xv * bv.x;
            state[1] = state[1] * ex + xv * bv.y;
            state[2] = state[2] * ex + xv * bv.z;
            state[3] = state[3] * ex + xv * bv.w;
            float cp = state[0] * cv.x + state[1] * cv.y + state[2] * cv.z + state[3] * cv.w;
            cp += __shfl_xor(cp, 1);
            cp += __shfl_xor(cp, 2);
            cp += __shfl_xor(cp, 4);
            cp += __shfl_xor(cp, 8);

            if (dsq == 0) {
                int tau = ck * CH + r;
                int tout; float val = cp;
                if (dir == 0) {
                    tout = tau + 1;
                    if (tau == L_SEQ - 1) { tout = 0; val = 0.f; }
                } else {
                    tout = L_SEQ - 2 - tau;
                    if (tau == L_SEQ - 1) { tout = L_SEQ - 1; val = 0.f; }
                }
                yout[((size_t)beta * L_SEQ + tout) * DINNER + h * 64 + quarter * 16 + hd] = val;
            }
        }

        if (ck + 1 < NCK) {
            if (tid < 144) {
#pragma unroll
                for (int r = 0; r < CH; ++r) sbuf[cb ^ 1][r][tid] = vals[r];
            } else if (tid < 144 + CH) {
                exs[cb ^ 1][tid - 144] = exv;
            }
        }
        __syncthreads();
    }
}

// ---------------- diag_heads = x . fc_D_w^T + Dp  (one wave per row) ------------------
__global__ __launch_bounds__(64)
void diag_kernel(const float* __restrict__ xBCc, const float* __restrict__ fcD,
                 const float* __restrict__ Dp, float* __restrict__ diag) {
    const int row = blockIdx.x;            // beta*L + t
    const int lane = threadIdx.x;
    const float* x = xBCc + (size_t)row * CONVDIM;   // channels 0..2047 = x_og
    float acc[NHEADS_];
#pragma unroll
    for (int hh = 0; hh < NHEADS_; ++hh) acc[hh] = 0.f;
    for (int k0 = 0; k0 < DINNER; k0 += 64) {
        float xv = x[k0 + lane];
#pragma unroll 8
        for (int hh = 0; hh < NHEADS_; ++hh)
            acc[hh] += xv * fcD[(size_t)hh * DINNER + k0 + lane];
    }
#pragma unroll
    for (int hh = 0; hh < NHEADS_; ++hh) {
        float v = acc[hh];
        v += __shfl_xor(v, 1);  v += __shfl_xor(v, 2);  v += __shfl_xor(v, 4);
        v += __shfl_xor(v, 8);  v += __shfl_xor(v, 16); v += __shfl_xor(v, 32);
        acc[hh] = v;
    }
    float outv = 0.f;
#pragma unroll
    for (int hh = 0; hh < NHEADS_; ++hh)
        if (lane == hh) outv = acc[hh];
    if (lane < NHEADS_) diag[(size_t)row * NHEADS_ + lane] = outv + Dp[lane];
}

// ---------------- combine + RMSNorm + silu(z) gate ------------------------------------
__global__ __launch_bounds__(256)
void combine_rms(const float* __restrict__ yfw, const float* __restrict__ ybw,
                 const float* __restrict__ xBCc, const float* __restrict__ diag,
                 const float* __restrict__ zxbcdt, const float* __restrict__ norm_w,
                 float* __restrict__ yout) {
    const int row = blockIdx.x;
    const int tid = threadIdx.x;
    const float* yfr = yfw + (size_t)row * DINNER;
    const float* ybr = ybw + (size_t)row * DINNER;
    const float* xr  = xBCc + (size_t)row * CONVDIM;
    const float* dg  = diag + (size_t)row * NHEADS_;
    const float* zr  = zxbcdt + (size_t)row * DINPROJ;   // channels 0..2047 = z
    float v[8];
    float ss = 0.f;
#pragma unroll
    for (int i = 0; i < 8; ++i) {
        int c = tid * 8 + i;
        float val = yfr[c] + ybr[c] + xr[c] * dg[c >> 6];
        v[i] = val;
        ss += val * val;
    }
    ss += __shfl_xor(ss, 1);  ss += __shfl_xor(ss, 2);  ss += __shfl_xor(ss, 4);
    ss += __shfl_xor(ss, 8);  ss += __shfl_xor(ss, 16); ss += __shfl_xor(ss, 32);
    __shared__ float wsum[4];
    if ((tid & 63) == 0) wsum[tid >> 6] = ss;
    __syncthreads();
    ss = wsum[0] + wsum[1] + wsum[2] + wsum[3];
    const float inv = rsqrtf(ss * (1.f / DINNER) + EPS_);
#pragma unroll
    for (int i = 0; i < 8; ++i) {
        int c = tid * 8 + i;
        float z = zr[c];
        yout[(size_t)row * DINNER + c] = norm_w[c] * v[i] * inv * silu_f(z);
    }
}

extern "C" void kernel_launch(void* const* d_in, const int* in_sizes, int n_in,
                              void* d_out, int out_size, void* d_ws, size_t ws_size,
                              hipStream_t stream) {
    const float* u       = (const float*)d_in[0];
    const float* W_in    = (const float*)d_in[1];
    const float* conv_w  = (const float*)d_in[2];
    const float* conv_b  = (const float*)d_in[3];
    const float* dt_bias = (const float*)d_in[4];
    const float* A_log   = (const float*)d_in[5];
    const float* Dp      = (const float*)d_in[6];
    const float* fc_D_w  = (const float*)d_in[7];
    const float* norm_w  = (const float*)d_in[8];
    const float* W_out   = (const float*)d_in[9];
    float* out = (float*)d_out;

    const int ROWS = BATCH_ * L_SEQ;     // 4096
    float* ws = (float*)d_ws;
    float* zxbcdt = ws;                                    // 4096*4416
    float* xBCc   = zxbcdt + (size_t)ROWS * DINPROJ;       // 4096*2304
    float* yfw    = xBCc   + (size_t)ROWS * CONVDIM;       // 4096*2048
    float* ybw    = yfw    + (size_t)ROWS * DINNER;        // 4096*2048
    float* diag   = ybw    + (size_t)ROWS * DINNER;        // 4096*32
    float* exbuf  = diag   + (size_t)ROWS * NHEADS_;       // 4*32*2048

    // 1. in_proj GEMM: zxbcdt = u @ W_in^T   (M=4096, N=4416, K=1024)
    dim3 g1(DINPROJ / 64, ROWS / 64);
    gemm_nt<64, 64, 16><<<g1, 256, 0, stream>>>(u, W_in, zxbcdt, ROWS, DINPROJ, DMODEL);

    // 2. depthwise conv + SiLU
    dim3 gc(CONVDIM / 256, L_SEQ / 16, BATCH_);
    conv_kernel<<<gc, 256, 0, stream>>>(zxbcdt, conv_w, conv_b, xBCc);

    // 2b. dt/ex precompute (4*2048*32 elements)
    dtexp_kernel<<<(4 * L_SEQ * NHEADS_) / 256, 256, 0, stream>>>(zxbcdt, dt_bias, A_log, exbuf);

    // 3. bidirectional selective scan (includes output shift + reversal)
    dim3 gs(NHEADS_, 4, 4);
    scan_kernel<<<gs, 256, 0, stream>>>(xBCc, exbuf, yfw, ybw);

    // 4. diag heads
    diag_kernel<<<ROWS, 64, 0, stream>>>(xBCc, fc_D_w, Dp, diag);

    // 5. combine + RMS norm + gate (in-place over yfw)
    combine_rms<<<ROWS, 256, 0, stream>>>(yfw, ybw, xBCc, diag, zxbcdt, norm_w, yfw);

    // 6. out_proj GEMM: out = y @ W_out^T   (M=4096, N=1024, K=2048)
    dim3 g3(DMODEL / 64, ROWS / 64);
    gemm_nt<64, 64, 16><<<g3, 256, 0, stream>>>(yfw, W_out, out, ROWS, DMODEL, DINNER);
}

// Round 4
// 1205.790 us; speedup vs baseline: 2.3521x; 1.2482x over previous
//
#include <hip/hip_runtime.h>
#include <cstdint>
#include <cstddef>

#define L_SEQ   2048
#define DMODEL  1024
#define DINNER  2048
#define NHEADS_ 32
#define HEADDIM_ 64
#define DSTATE  64
#define CONVDIM 2304
#define DINPROJ 4416
#define DINPROJ_P 4480   // padded to 128-multiple for MFMA tiles
#define BATCH_  2
#define EPS_    1e-5f
#define CH      16       // scan chunk (time steps staged per LDS buffer)

typedef __attribute__((ext_vector_type(8))) short bf16x8;
typedef __attribute__((ext_vector_type(4))) float f32x4;
typedef unsigned short ushort_t;
typedef unsigned int uint_t;

__device__ __forceinline__ float silu_f(float v) { return v / (1.f + __expf(-v)); }
__device__ __forceinline__ ushort_t f2bf(float f) {
    uint_t u = __float_as_uint(f);
    return (ushort_t)((u + 0x7FFFu + ((u >> 16) & 1u)) >> 16);   // RNE
}

// ---------------- fp32 -> bf16 conversion (plain) -------------------------------------
__global__ __launch_bounds__(256)
void cvt_bf16(const float* __restrict__ src, ushort_t* __restrict__ dst) {
    const size_t i4 = (size_t)blockIdx.x * 256 + threadIdx.x;
    float4 v = reinterpret_cast<const float4*>(src)[i4];
    ushort_t* d = dst + i4 * 4;
    d[0] = f2bf(v.x); d[1] = f2bf(v.y); d[2] = f2bf(v.z); d[3] = f2bf(v.w);
}

// ---------------- W_in fp32[4416][1024] -> bf16[4480][1024] zero-padded ---------------
__global__ __launch_bounds__(256)
void cvt_bf16_pad(const float* __restrict__ src, ushort_t* __restrict__ dst) {
    const size_t i4 = (size_t)blockIdx.x * 256 + threadIdx.x;   // over 4480*1024/4
    const int row = (int)(i4 / (DMODEL / 4));
    float4 v = make_float4(0.f, 0.f, 0.f, 0.f);
    if (row < DINPROJ) v = reinterpret_cast<const float4*>(src)[i4];
    ushort_t* d = dst + i4 * 4;
    d[0] = f2bf(v.x); d[1] = f2bf(v.y); d[2] = f2bf(v.z); d[3] = f2bf(v.w);
}

// ---------------- bf16 MFMA GEMM: C[M][N](f32) = A[M][K](bf16) * B[N][K](bf16)^T ------
// 256 threads = 4 waves in WGM x WGN grid; each wave: FM x FN fragments of 16x16.
// BK = 32 (one 16x16x32 MFMA per fragment per K-step). LDS XOR-swizzled (T2).
template<int BM, int BN, int WGM, int WGN, int FM, int FN>
__global__ __launch_bounds__(256)
void gemm_nt_mfma(const ushort_t* __restrict__ A, const ushort_t* __restrict__ B,
                  float* __restrict__ C, int M, int N, int K) {
    __shared__ __align__(16) short As[BM * 32];
    __shared__ __align__(16) short Bs[BN * 32];
    const int tid = threadIdx.x;
    const int wave = tid >> 6, lane = tid & 63;
    const int wr = wave / WGN, wc = wave % WGN;
    const int bm = blockIdx.y * BM, bn = blockIdx.x * BN;
    const int srow = tid >> 2;              // 0..63 staging row per pass
    const int skoff = (tid & 3) * 8;        // bf16 elems along K
    const int fr = lane & 15, kg = lane >> 4;

    f32x4 acc[FM][FN];
#pragma unroll
    for (int m = 0; m < FM; ++m)
#pragma unroll
        for (int n = 0; n < FN; ++n) acc[m][n] = (f32x4){0.f, 0.f, 0.f, 0.f};

    for (int k0 = 0; k0 < K; k0 += 32) {
        uint4 aval[BM / 64], bval[BN / 64];
#pragma unroll
        for (int p = 0; p < BM / 64; ++p)
            aval[p] = *reinterpret_cast<const uint4*>(&A[(size_t)(bm + p * 64 + srow) * K + k0 + skoff]);
#pragma unroll
        for (int p = 0; p < BN / 64; ++p)
            bval[p] = *reinterpret_cast<const uint4*>(&B[(size_t)(bn + p * 64 + srow) * K + k0 + skoff]);
        __syncthreads();     // previous iteration's readers done
#pragma unroll
        for (int p = 0; p < BM / 64; ++p) {
            int row = p * 64 + srow;
            int byte = (row * 64 + skoff * 2) ^ ((row & 7) << 4);
            *reinterpret_cast<uint4*>(reinterpret_cast<char*>(As) + byte) = aval[p];
        }
#pragma unroll
        for (int p = 0; p < BN / 64; ++p) {
            int row = p * 64 + srow;
            int byte = (row * 64 + skoff * 2) ^ ((row & 7) << 4);
            *reinterpret_cast<uint4*>(reinterpret_cast<char*>(Bs) + byte) = bval[p];
        }
        __syncthreads();

        bf16x8 af[FM], bfv[FN];
#pragma unroll
        for (int m = 0; m < FM; ++m) {
            int row = wr * FM * 16 + m * 16 + fr;
            int byte = (row * 64 + kg * 16) ^ ((row & 7) << 4);
            af[m] = *reinterpret_cast<const bf16x8*>(reinterpret_cast<const char*>(As) + byte);
        }
#pragma unroll
        for (int n = 0; n < FN; ++n) {
            int row = wc * FN * 16 + n * 16 + fr;
            int byte = (row * 64 + kg * 16) ^ ((row & 7) << 4);
            bfv[n] = *reinterpret_cast<const bf16x8*>(reinterpret_cast<const char*>(Bs) + byte);
        }
#pragma unroll
        for (int m = 0; m < FM; ++m)
#pragma unroll
            for (int n = 0; n < FN; ++n)
                acc[m][n] = __builtin_amdgcn_mfma_f32_16x16x32_bf16(af[m], bfv[n], acc[m][n], 0, 0, 0);
    }

    const int rg = lane >> 4;   // C/D: col = lane&15, row = rg*4 + r
#pragma unroll
    for (int m = 0; m < FM; ++m)
#pragma unroll
        for (int n = 0; n < FN; ++n) {
            int col = bn + wc * FN * 16 + n * 16 + fr;
#pragma unroll
            for (int r = 0; r < 4; ++r) {
                int rowg = bm + wr * FM * 16 + m * 16 + rg * 4 + r;
                C[(size_t)rowg * N + col] = acc[m][n][r];
            }
        }
}

// ---------------- depthwise conv (k=7, pad 3) + bias + SiLU --------------------------
__global__ __launch_bounds__(256)
void conv_kernel(const float* __restrict__ zxbcdt, const float* __restrict__ conv_w,
                 const float* __restrict__ conv_b, float* __restrict__ xBCc) {
    const int c = blockIdx.x * 256 + threadIdx.x;   // channel 0..2303
    const int t0 = blockIdx.y * 16;
    const int beta = blockIdx.z;
    float w[7];
#pragma unroll
    for (int k = 0; k < 7; ++k) w[k] = conv_w[c * 7 + k];
    const float bias = conv_b[c];
    const float* in = zxbcdt + (size_t)beta * L_SEQ * DINPROJ_P + DINNER + c;
    float* outp = xBCc + (size_t)beta * L_SEQ * CONVDIM + c;
    float win[7];
#pragma unroll
    for (int j = 0; j < 6; ++j) {
        int t = t0 - 3 + j;
        win[j] = (t >= 0 && t < L_SEQ) ? in[(size_t)t * DINPROJ_P] : 0.f;
    }
    for (int i = 0; i < 16; ++i) {
        int t = t0 + i;
        int tl = t + 3;
        win[6] = (tl < L_SEQ) ? in[(size_t)tl * DINPROJ_P] : 0.f;
        float acc = bias;
#pragma unroll
        for (int k = 0; k < 7; ++k) acc += win[k] * w[k];
        outp[(size_t)t * CONVDIM] = silu_f(acc);
#pragma unroll
        for (int j = 0; j < 6; ++j) win[j] = win[j + 1];
    }
}

// ---------------- dt/ex precompute: ex[bd][h][tau] = exp(A_h * softplus(dt_raw+bias)) --
__global__ __launch_bounds__(256)
void dtexp_kernel(const float* __restrict__ zxbcdt, const float* __restrict__ dt_bias,
                  const float* __restrict__ A_log, float* __restrict__ exbuf) {
    const int idx = blockIdx.x * 256 + threadIdx.x;     // 4*2048*32
    const int h   = idx & 31;
    const int tau = (idx >> 5) & (L_SEQ - 1);
    const int bd  = idx >> 16;
    const int dir = bd >> 1, beta = bd & 1;
    const int tt  = dir ? (L_SEQ - 1 - tau) : tau;
    const float dtraw = zxbcdt[((size_t)beta * L_SEQ + tt) * DINPROJ_P + DINNER + CONVDIM + dir * NHEADS_ + h];
    const float Ah = -__expf(A_log[h]);
    const float dtv = dtraw + dt_bias[h];
    const float sp = (dtv > 15.f) ? dtv : log1pf(__expf(dtv));
    exbuf[((size_t)bd * NHEADS_ + h) * L_SEQ + tau] = __expf(Ah * sp);
}

// ---------------- sequential selective scan, chunked LDS staging ----------------------
__global__ __launch_bounds__(256)
void scan_kernel(const float* __restrict__ xBCc, const float* __restrict__ exbuf,
                 float* __restrict__ yfw, float* __restrict__ ybw) {
    const int h = blockIdx.x;
    const int bd = blockIdx.y;
    const int quarter = blockIdx.z;
    const int dir = bd >> 1, beta = bd & 1;
    const int tid = threadIdx.x;
    const int hd = tid >> 4;        // 0..15 (local head-dim row)
    const int dsq = tid & 15;       // 4 dstate elems each

    float state[4] = {0.f, 0.f, 0.f, 0.f};

    // row layout: [0..15]=x(quarter), [16..79]=B, [80..143]=C
    __shared__ float sbuf[2][CH][144];
    __shared__ float exs[2][CH];
    float* yout = dir ? ybw : yfw;

    const float* src = nullptr;
    if (tid < 144) {
        int col = (tid < 16) ? (h * 64 + quarter * 16 + tid)
                             : (DINNER + dir * 128 + (tid - 16));
        src = xBCc + (size_t)beta * L_SEQ * CONVDIM + col;
    }
    const float* exsrc = exbuf + ((size_t)bd * NHEADS_ + h) * L_SEQ;

    float vals[CH];
    float exv = 0.f;
    auto issue_chunk = [&](int ck) {
        if (tid < 144) {
#pragma unroll
            for (int r = 0; r < CH; ++r) {
                int tau = ck * CH + r;
                int tt = dir ? (L_SEQ - 1 - tau) : tau;
                vals[r] = src[(size_t)tt * CONVDIM];
            }
        } else if (tid < 144 + CH) {
            exv = exsrc[ck * CH + (tid - 144)];
        }
    };

    issue_chunk(0);
    if (tid < 144) {
#pragma unroll
        for (int r = 0; r < CH; ++r) sbuf[0][r][tid] = vals[r];
    } else if (tid < 144 + CH) {
        exs[0][tid - 144] = exv;
    }
    __syncthreads();

    const int NCK = L_SEQ / CH;
    for (int ck = 0; ck < NCK; ++ck) {
        const int cb = ck & 1;
        if (ck + 1 < NCK) issue_chunk(ck + 1);   // overlap with compute below

#pragma unroll
        for (int r = 0; r < CH; ++r) {
            const float ex = exs[cb][r];
            const float xv = sbuf[cb][r][hd];
            const float4 bv = *reinterpret_cast<const float4*>(&sbuf[cb][r][16 + dsq * 4]);
            const float4 cv = *reinterpret_cast<const float4*>(&sbuf[cb][r][80 + dsq * 4]);
            state[0] = state[0] * ex + xv * bv.x;
            state[1] = state[1] * ex + xv * bv.y;
            state[2] = state[2] * ex + xv * bv.z;
            state[3] = state[3] * ex + xv * bv.w;
            float cp = state[0] * cv.x + state[1] * cv.y + state[2] * cv.z + state[3] * cv.w;
            cp += __shfl_xor(cp, 1);
            cp += __shfl_xor(cp, 2);
            cp += __shfl_xor(cp, 4);
            cp += __shfl_xor(cp, 8);

            if (dsq == 0) {
                int tau = ck * CH + r;
                int tout; float val = cp;
                if (dir == 0) {
                    tout = tau + 1;
                    if (tau == L_SEQ - 1) { tout = 0; val = 0.f; }
                } else {
                    tout = L_SEQ - 2 - tau;
                    if (tau == L_SEQ - 1) { tout = L_SEQ - 1; val = 0.f; }
                }
                yout[((size_t)beta * L_SEQ + tout) * DINNER + h * 64 + quarter * 16 + hd] = val;
            }
        }

        if (ck + 1 < NCK) {
            if (tid < 144) {
#pragma unroll
                for (int r = 0; r < CH; ++r) sbuf[cb ^ 1][r][tid] = vals[r];
            } else if (tid < 144 + CH) {
                exs[cb ^ 1][tid - 144] = exv;
            }
        }
        __syncthreads();
    }
}

// ---------------- diag_heads = x . fc_D_w^T + Dp  (one wave per row) ------------------
__global__ __launch_bounds__(64)
void diag_kernel(const float* __restrict__ xBCc, const float* __restrict__ fcD,
                 const float* __restrict__ Dp, float* __restrict__ diag) {
    const int row = blockIdx.x;            // beta*L + t
    const int lane = threadIdx.x;
    const float* x = xBCc + (size_t)row * CONVDIM;   // channels 0..2047 = x_og
    float acc[NHEADS_];
#pragma unroll
    for (int hh = 0; hh < NHEADS_; ++hh) acc[hh] = 0.f;
    for (int k0 = 0; k0 < DINNER; k0 += 64) {
        float xv = x[k0 + lane];
#pragma unroll 8
        for (int hh = 0; hh < NHEADS_; ++hh)
            acc[hh] += xv * fcD[(size_t)hh * DINNER + k0 + lane];
    }
#pragma unroll
    for (int hh = 0; hh < NHEADS_; ++hh) {
        float v = acc[hh];
        v += __shfl_xor(v, 1);  v += __shfl_xor(v, 2);  v += __shfl_xor(v, 4);
        v += __shfl_xor(v, 8);  v += __shfl_xor(v, 16); v += __shfl_xor(v, 32);
        acc[hh] = v;
    }
    float outv = 0.f;
#pragma unroll
    for (int hh = 0; hh < NHEADS_; ++hh)
        if (lane == hh) outv = acc[hh];
    if (lane < NHEADS_) diag[(size_t)row * NHEADS_ + lane] = outv + Dp[lane];
}

// ---------------- combine + RMSNorm + silu(z) gate -> bf16 y ---------------------------
__global__ __launch_bounds__(256)
void combine_rms(const float* __restrict__ yfw, const float* __restrict__ ybw,
                 const float* __restrict__ xBCc, const float* __restrict__ diag,
                 const float* __restrict__ zxbcdt, const float* __restrict__ norm_w,
                 ushort_t* __restrict__ ybf) {
    const int row = blockIdx.x;
    const int tid = threadIdx.x;
    const float* yfr = yfw + (size_t)row * DINNER;
    const float* ybr = ybw + (size_t)row * DINNER;
    const float* xr  = xBCc + (size_t)row * CONVDIM;
    const float* dg  = diag + (size_t)row * NHEADS_;
    const float* zr  = zxbcdt + (size_t)row * DINPROJ_P;   // channels 0..2047 = z
    float v[8];
    float ss = 0.f;
#pragma unroll
    for (int i = 0; i < 8; ++i) {
        int c = tid * 8 + i;
        float val = yfr[c] + ybr[c] + xr[c] * dg[c >> 6];
        v[i] = val;
        ss += val * val;
    }
    ss += __shfl_xor(ss, 1);  ss += __shfl_xor(ss, 2);  ss += __shfl_xor(ss, 4);
    ss += __shfl_xor(ss, 8);  ss += __shfl_xor(ss, 16); ss += __shfl_xor(ss, 32);
    __shared__ float wsum[4];
    if ((tid & 63) == 0) wsum[tid >> 6] = ss;
    __syncthreads();
    ss = wsum[0] + wsum[1] + wsum[2] + wsum[3];
    const float inv = rsqrtf(ss * (1.f / DINNER) + EPS_);
#pragma unroll
    for (int i = 0; i < 8; ++i) {
        int c = tid * 8 + i;
        float z = zr[c];
        ybf[(size_t)row * DINNER + c] = f2bf(norm_w[c] * v[i] * inv * silu_f(z));
    }
}

extern "C" void kernel_launch(void* const* d_in, const int* in_sizes, int n_in,
                              void* d_out, int out_size, void* d_ws, size_t ws_size,
                              hipStream_t stream) {
    const float* u       = (const float*)d_in[0];
    const float* W_in    = (const float*)d_in[1];
    const float* conv_w  = (const float*)d_in[2];
    const float* conv_b  = (const float*)d_in[3];
    const float* dt_bias = (const float*)d_in[4];
    const float* A_log   = (const float*)d_in[5];
    const float* Dp      = (const float*)d_in[6];
    const float* fc_D_w  = (const float*)d_in[7];
    const float* norm_w  = (const float*)d_in[8];
    const float* W_out   = (const float*)d_in[9];
    float* out = (float*)d_out;

    const int ROWS = BATCH_ * L_SEQ;     // 4096
    float* ws = (float*)d_ws;
    float* zxbcdt = ws;                                      // 4096*4480
    float* xBCc   = zxbcdt + (size_t)ROWS * DINPROJ_P;       // 4096*2304
    float* yfw    = xBCc   + (size_t)ROWS * CONVDIM;         // 4096*2048
    float* ybw    = yfw    + (size_t)ROWS * DINNER;          // 4096*2048
    float* diag   = ybw    + (size_t)ROWS * DINNER;          // 4096*32
    float* exbuf  = diag   + (size_t)ROWS * NHEADS_;         // 4*32*2048
    ushort_t* ubf  = (ushort_t*)(exbuf + (size_t)4 * NHEADS_ * L_SEQ);
    ushort_t* wibf = ubf  + (size_t)ROWS * DMODEL;           // 4480*1024
    ushort_t* wobf = wibf + (size_t)DINPROJ_P * DMODEL;      // 1024*2048
    ushort_t* ybf  = wobf + (size_t)DMODEL * DINNER;         // 4096*2048

    // 0. dtype conversions
    cvt_bf16<<<(ROWS * DMODEL) / 1024, 256, 0, stream>>>(u, ubf);
    cvt_bf16_pad<<<(DINPROJ_P * DMODEL) / 1024, 256, 0, stream>>>(W_in, wibf);
    cvt_bf16<<<(DMODEL * DINNER) / 1024, 256, 0, stream>>>(W_out, wobf);

    // 1. in_proj GEMM (MFMA): zxbcdt = u @ W_in^T   (M=4096, N=4480pad, K=1024)
    dim3 g1(DINPROJ_P / 128, ROWS / 128);
    gemm_nt_mfma<128, 128, 2, 2, 4, 4><<<g1, 256, 0, stream>>>(ubf, wibf, zxbcdt, ROWS, DINPROJ_P, DMODEL);

    // 2. depthwise conv + SiLU
    dim3 gc(CONVDIM / 256, L_SEQ / 16, BATCH_);
    conv_kernel<<<gc, 256, 0, stream>>>(zxbcdt, conv_w, conv_b, xBCc);

    // 2b. dt/ex precompute
    dtexp_kernel<<<(4 * L_SEQ * NHEADS_) / 256, 256, 0, stream>>>(zxbcdt, dt_bias, A_log, exbuf);

    // 3. bidirectional selective scan
    dim3 gs(NHEADS_, 4, 4);
    scan_kernel<<<gs, 256, 0, stream>>>(xBCc, exbuf, yfw, ybw);

    // 4. diag heads
    diag_kernel<<<ROWS, 64, 0, stream>>>(xBCc, fc_D_w, Dp, diag);

    // 5. combine + RMS norm + gate -> bf16
    combine_rms<<<ROWS, 256, 0, stream>>>(yfw, ybw, xBCc, diag, zxbcdt, norm_w, ybf);

    // 6. out_proj GEMM (MFMA): out = y @ W_out^T   (M=4096, N=1024, K=2048)
    dim3 g3(DMODEL / 64, ROWS / 128);
    gemm_nt_mfma<128, 64, 2, 2, 4, 2><<<g3, 256, 0, stream>>>(ybf, wobf, out, ROWS, DMODEL, DINNER);
}

// Round 6
// 821.058 us; speedup vs baseline: 3.4543x; 1.4686x over previous
//
#include <hip/hip_runtime.h>
#include <cstdint>
#include <cstddef>

#define L_SEQ   2048
#define DMODEL  1024
#define DINNER  2048
#define NHEADS_ 32
#define HEADDIM_ 64
#define DSTATE  64
#define CONVDIM 2304
#define DINPROJ 4416
#define DINPROJ_P 4480   // padded to 128-multiple for MFMA tiles
#define XDT     2368     // xBC (2304) + dt (64) fp32 staging width
#define BATCH_  2
#define EPS_    1e-5f
#define PITCH   72       // LDS tile pitch in bf16 elems (144B rows)

typedef __attribute__((ext_vector_type(8))) short bf16x8;
typedef __attribute__((ext_vector_type(4))) float f32x4;
typedef unsigned short ushort_t;
typedef unsigned int uint_t;

__device__ __forceinline__ float silu_f(float v) { return v / (1.f + __expf(-v)); }
__device__ __forceinline__ ushort_t f2bf(float f) {
    uint_t u = __float_as_uint(f);
    return (ushort_t)((u + 0x7FFFu + ((u >> 16) & 1u)) >> 16);   // RNE
}
__device__ __forceinline__ float bf2f(ushort_t u) {
    return __uint_as_float(((uint_t)u) << 16);
}

// ---------------- fp32 -> bf16 conversion (plain) -------------------------------------
__global__ __launch_bounds__(256)
void cvt_bf16(const float* __restrict__ src, ushort_t* __restrict__ dst) {
    const size_t i4 = (size_t)blockIdx.x * 256 + threadIdx.x;
    float4 v = reinterpret_cast<const float4*>(src)[i4];
    ushort_t* d = dst + i4 * 4;
    d[0] = f2bf(v.x); d[1] = f2bf(v.y); d[2] = f2bf(v.z); d[3] = f2bf(v.w);
}

// ---------------- W_in fp32[4416][1024] -> bf16[4480][1024] zero-padded ---------------
__global__ __launch_bounds__(256)
void cvt_bf16_pad(const float* __restrict__ src, ushort_t* __restrict__ dst) {
    const size_t i4 = (size_t)blockIdx.x * 256 + threadIdx.x;   // over 4480*1024/4
    const int row = (int)(i4 / (DMODEL / 4));
    float4 v = make_float4(0.f, 0.f, 0.f, 0.f);
    if (row < DINPROJ) v = reinterpret_cast<const float4*>(src)[i4];
    ushort_t* d = dst + i4 * 4;
    d[0] = f2bf(v.x); d[1] = f2bf(v.y); d[2] = f2bf(v.z); d[3] = f2bf(v.w);
}

// ---------------- bf16 MFMA GEMM: C = A[M][K] * B[N][K]^T -----------------------------
// MODE 0: plain fp32 C.  MODE 1: split write (col<2048 -> bf16 zbf; 2048..4415 -> fp32
// xdt at col-2048 with row stride XDT; cols >= 4416 dropped).
template<int BM, int BN, int WGM, int WGN, int FM, int FN, int MODE>
__global__ __launch_bounds__(256)
void gemm_nt_mfma(const ushort_t* __restrict__ A, const ushort_t* __restrict__ B,
                  float* __restrict__ C, ushort_t* __restrict__ zout,
                  float* __restrict__ xdt, int M, int N, int K) {
    __shared__ __align__(16) short As[BM * 32];
    __shared__ __align__(16) short Bs[BN * 32];
    const int tid = threadIdx.x;
    const int wave = tid >> 6, lane = tid & 63;
    const int wr = wave / WGN, wc = wave % WGN;
    const int bm = blockIdx.y * BM, bn = blockIdx.x * BN;
    const int srow = tid >> 2;              // 0..63 staging row per pass
    const int skoff = (tid & 3) * 8;        // bf16 elems along K
    const int fr = lane & 15, kg = lane >> 4;

    f32x4 acc[FM][FN];
#pragma unroll
    for (int m = 0; m < FM; ++m)
#pragma unroll
        for (int n = 0; n < FN; ++n) acc[m][n] = (f32x4){0.f, 0.f, 0.f, 0.f};

    for (int k0 = 0; k0 < K; k0 += 32) {
        uint4 aval[BM / 64], bval[BN / 64];
#pragma unroll
        for (int p = 0; p < BM / 64; ++p)
            aval[p] = *reinterpret_cast<const uint4*>(&A[(size_t)(bm + p * 64 + srow) * K + k0 + skoff]);
#pragma unroll
        for (int p = 0; p < BN / 64; ++p)
            bval[p] = *reinterpret_cast<const uint4*>(&B[(size_t)(bn + p * 64 + srow) * K + k0 + skoff]);
        __syncthreads();
#pragma unroll
        for (int p = 0; p < BM / 64; ++p) {
            int row = p * 64 + srow;
            int byte = (row * 64 + skoff * 2) ^ ((row & 7) << 4);
            *reinterpret_cast<uint4*>(reinterpret_cast<char*>(As) + byte) = aval[p];
        }
#pragma unroll
        for (int p = 0; p < BN / 64; ++p) {
            int row = p * 64 + srow;
            int byte = (row * 64 + skoff * 2) ^ ((row & 7) << 4);
            *reinterpret_cast<uint4*>(reinterpret_cast<char*>(Bs) + byte) = bval[p];
        }
        __syncthreads();

        bf16x8 af[FM], bfv[FN];
#pragma unroll
        for (int m = 0; m < FM; ++m) {
            int row = wr * FM * 16 + m * 16 + fr;
            int byte = (row * 64 + kg * 16) ^ ((row & 7) << 4);
            af[m] = *reinterpret_cast<const bf16x8*>(reinterpret_cast<const char*>(As) + byte);
        }
#pragma unroll
        for (int n = 0; n < FN; ++n) {
            int row = wc * FN * 16 + n * 16 + fr;
            int byte = (row * 64 + kg * 16) ^ ((row & 7) << 4);
            bfv[n] = *reinterpret_cast<const bf16x8*>(reinterpret_cast<const char*>(Bs) + byte);
        }
#pragma unroll
        for (int m = 0; m < FM; ++m)
#pragma unroll
            for (int n = 0; n < FN; ++n)
                acc[m][n] = __builtin_amdgcn_mfma_f32_16x16x32_bf16(af[m], bfv[n], acc[m][n], 0, 0, 0);
    }

    const int rg = lane >> 4;   // C/D: col = lane&15, row = rg*4 + r
#pragma unroll
    for (int m = 0; m < FM; ++m)
#pragma unroll
        for (int n = 0; n < FN; ++n) {
            int col = bn + wc * FN * 16 + n * 16 + fr;
#pragma unroll
            for (int r = 0; r < 4; ++r) {
                int rowg = bm + wr * FM * 16 + m * 16 + rg * 4 + r;
                float v = acc[m][n][r];
                if (MODE == 0) {
                    C[(size_t)rowg * N + col] = v;
                } else {
                    if (col < DINNER)       zout[(size_t)rowg * DINNER + col] = f2bf(v);
                    else if (col < DINPROJ) xdt[(size_t)rowg * XDT + (col - DINNER)] = v;
                }
            }
        }
}

// ---------------- depthwise conv + bias + SiLU -> bf16 xBC ----------------------------
__global__ __launch_bounds__(256)
void conv_kernel(const float* __restrict__ xdt, const float* __restrict__ conv_w,
                 const float* __restrict__ conv_b, ushort_t* __restrict__ xBCbf) {
    const int c = blockIdx.x * 256 + threadIdx.x;   // channel 0..2303
    const int t0 = blockIdx.y * 16;
    const int beta = blockIdx.z;
    float w[7];
#pragma unroll
    for (int k = 0; k < 7; ++k) w[k] = conv_w[c * 7 + k];
    const float bias = conv_b[c];
    const float* in = xdt + (size_t)beta * L_SEQ * XDT + c;
    float win[7];
#pragma unroll
    for (int j = 0; j < 6; ++j) {
        int t = t0 - 3 + j;
        win[j] = (t >= 0 && t < L_SEQ) ? in[(size_t)t * XDT] : 0.f;
    }
    for (int i = 0; i < 16; ++i) {
        int t = t0 + i;
        int tl = t + 3;
        win[6] = (tl < L_SEQ) ? in[(size_t)tl * XDT] : 0.f;
        float acc = bias;
#pragma unroll
        for (int k = 0; k < 7; ++k) acc += win[k] * w[k];
        xBCbf[((size_t)beta * L_SEQ + t) * CONVDIM + c] = f2bf(silu_f(acc));
#pragma unroll
        for (int j = 0; j < 6; ++j) win[j] = win[j + 1];
    }
}

// ---------------- log-decay precompute: la[bd][h][tau] = A_h * softplus(dt+bias) ------
__global__ __launch_bounds__(256)
void dtla_kernel(const float* __restrict__ xdt, const float* __restrict__ dt_bias,
                 const float* __restrict__ A_log, float* __restrict__ labuf) {
    const int idx = blockIdx.x * 256 + threadIdx.x;     // 4*2048*32
    const int h   = idx & 31;
    const int tau = (idx >> 5) & (L_SEQ - 1);
    const int bd  = idx >> 16;
    const int dir = bd >> 1, beta = bd & 1;
    const int tt  = dir ? (L_SEQ - 1 - tau) : tau;
    const float dtraw = xdt[((size_t)beta * L_SEQ + tt) * XDT + CONVDIM + dir * NHEADS_ + h];
    const float Ah = -__expf(A_log[h]);
    const float dtv = dtraw + dt_bias[h];
    const float sp = (dtv > 15.f) ? dtv : log1pf(__expf(dtv));
    labuf[((size_t)bd * NHEADS_ + h) * L_SEQ + tau] = Ah * sp;
}

// ---------------- SSD chunk kernel (K_A): chunk-parallel intra work --------------------
// grid = (chunk 0..31, h 0..31, bd 0..3); 256 threads = 4 waves (2x2).
// ls = in-chunk inclusive cum log-decay; P=exp(ls) -> Pbuf; G=C.B^T;
// M=mask*exp(ls_i-ls_j)*G; Y_intra = M @ X -> bf16 directly into shifted yfw/ybw;
// S_delta = X^T @ (w*B) -> sdel fp32 (w_j = exp(ls63-ls_j)).
__global__ __launch_bounds__(256)
void ssd_chunk_kernel(const ushort_t* __restrict__ xBCbf, const float* __restrict__ labuf,
                      float* __restrict__ Pbuf, float* __restrict__ sdel,
                      ushort_t* __restrict__ yfw, ushort_t* __restrict__ ybw) {
    const int c  = blockIdx.x;
    const int h  = blockIdx.y;
    const int bd = blockIdx.z;
    const int dir = bd >> 1, beta = bd & 1;
    const int tid = threadIdx.x;
    const int wave = tid >> 6, lane = tid & 63;
    const int wr = wave >> 1, wc = wave & 1;
    const int fr = lane & 15, kg = lane >> 4, rg = lane >> 4;

    __shared__ short Bs[64 * PITCH], Cs[64 * PITCH], XTs[64 * PITCH],
                     BTs[64 * PITCH], Ms[64 * PITCH];
    __shared__ float lslds[64];

    // ---- stage: row = tid>>2 (time), seg = tid&3 ----
    const int row = tid >> 2, seg = tid & 3;
    const int tau_r = c * 64 + row;
    const int tt = dir ? (L_SEQ - 1 - tau_r) : tau_r;
    const ushort_t* gbase = xBCbf + ((size_t)beta * L_SEQ + tt) * CONVDIM;

    union U4 { uint4 v; ushort_t s[8]; };
    U4 x0, x1, b0, b1, c0, c1;
    x0.v = *reinterpret_cast<const uint4*>(gbase + h * 64 + seg * 16);
    x1.v = *reinterpret_cast<const uint4*>(gbase + h * 64 + seg * 16 + 8);
    b0.v = *reinterpret_cast<const uint4*>(gbase + DINNER + dir * 128 + seg * 16);
    b1.v = *reinterpret_cast<const uint4*>(gbase + DINNER + dir * 128 + seg * 16 + 8);
    c0.v = *reinterpret_cast<const uint4*>(gbase + DINNER + dir * 128 + 64 + seg * 16);
    c1.v = *reinterpret_cast<const uint4*>(gbase + DINNER + dir * 128 + 64 + seg * 16 + 8);

    *reinterpret_cast<uint4*>(&Bs[row * PITCH + seg * 16])     = b0.v;
    *reinterpret_cast<uint4*>(&Bs[row * PITCH + seg * 16 + 8]) = b1.v;
    *reinterpret_cast<uint4*>(&Cs[row * PITCH + seg * 16])     = c0.v;
    *reinterpret_cast<uint4*>(&Cs[row * PITCH + seg * 16 + 8]) = c1.v;
#pragma unroll
    for (int k = 0; k < 8; ++k) {
        XTs[(seg * 16 + k) * PITCH + row]     = x0.s[k];
        XTs[(seg * 16 + 8 + k) * PITCH + row] = x1.s[k];
    }

    // ---- in-chunk inclusive log-decay scan (wave 0) ----
    if (tid < 64) {
        float v = labuf[((size_t)bd * NHEADS_ + h) * L_SEQ + c * 64 + tid];
#pragma unroll
        for (int d = 1; d < 64; d <<= 1) {
            float t = __shfl_up(v, d);
            if (lane >= d) v += t;
        }
        lslds[tid] = v;
        Pbuf[((size_t)bd * NHEADS_ + h) * L_SEQ + c * 64 + tid] = __expf(v);
    }
    __syncthreads();

    // ---- BT scatter with w_j = exp(ls63 - ls_j) baked in ----
    {
        const float wrow = __expf(lslds[63] - lslds[row]);
#pragma unroll
        for (int k = 0; k < 8; ++k) {
            BTs[(seg * 16 + k) * PITCH + row]     = (short)f2bf(bf2f(b0.s[k]) * wrow);
            BTs[(seg * 16 + 8 + k) * PITCH + row] = (short)f2bf(bf2f(b1.s[k]) * wrow);
        }
    }

    // ---- G = C @ B^T ----
    f32x4 accg[2][2];
#pragma unroll
    for (int mi = 0; mi < 2; ++mi)
#pragma unroll
        for (int nj = 0; nj < 2; ++nj) accg[mi][nj] = (f32x4){0.f, 0.f, 0.f, 0.f};
#pragma unroll
    for (int s = 0; s < 2; ++s) {
        int koff = kg * 8 + s * 32;
        bf16x8 af[2], bfv[2];
#pragma unroll
        for (int mi = 0; mi < 2; ++mi)
            af[mi] = *reinterpret_cast<const bf16x8*>(&Cs[(wr * 32 + mi * 16 + fr) * PITCH + koff]);
#pragma unroll
        for (int nj = 0; nj < 2; ++nj)
            bfv[nj] = *reinterpret_cast<const bf16x8*>(&Bs[(wc * 32 + nj * 16 + fr) * PITCH + koff]);
#pragma unroll
        for (int mi = 0; mi < 2; ++mi)
#pragma unroll
            for (int nj = 0; nj < 2; ++nj)
                accg[mi][nj] = __builtin_amdgcn_mfma_f32_16x16x32_bf16(af[mi], bfv[nj], accg[mi][nj], 0, 0, 0);
    }

    // ---- M = mask .* exp(ls_i - ls_j) .* G -> bf16 LDS ----
#pragma unroll
    for (int mi = 0; mi < 2; ++mi)
#pragma unroll
        for (int nj = 0; nj < 2; ++nj) {
            int j = wc * 32 + nj * 16 + fr;
            float lsj = lslds[j];
#pragma unroll
            for (int r = 0; r < 4; ++r) {
                int i = wr * 32 + mi * 16 + rg * 4 + r;
                float v = accg[mi][nj][r];
                v = (i >= j) ? v * __expf(lslds[i] - lsj) : 0.f;
                Ms[i * PITCH + j] = (short)f2bf(v);
            }
        }
    __syncthreads();

    // ---- Y_intra = M @ X ; S_delta = X^T @ Bw ----
    f32x4 accy[2][2], accs[2][2];
#pragma unroll
    for (int mi = 0; mi < 2; ++mi)
#pragma unroll
        for (int nj = 0; nj < 2; ++nj) {
            accy[mi][nj] = (f32x4){0.f, 0.f, 0.f, 0.f};
            accs[mi][nj] = (f32x4){0.f, 0.f, 0.f, 0.f};
        }
#pragma unroll
    for (int s = 0; s < 2; ++s) {
        int koff = kg * 8 + s * 32;
        bf16x8 am[2], axt[2], bxt[2], bbt[2];
#pragma unroll
        for (int mi = 0; mi < 2; ++mi) {
            am[mi]  = *reinterpret_cast<const bf16x8*>(&Ms[(wr * 32 + mi * 16 + fr) * PITCH + koff]);
            axt[mi] = *reinterpret_cast<const bf16x8*>(&XTs[(wr * 32 + mi * 16 + fr) * PITCH + koff]);
        }
#pragma unroll
        for (int nj = 0; nj < 2; ++nj) {
            bxt[nj] = *reinterpret_cast<const bf16x8*>(&XTs[(wc * 32 + nj * 16 + fr) * PITCH + koff]);
            bbt[nj] = *reinterpret_cast<const bf16x8*>(&BTs[(wc * 32 + nj * 16 + fr) * PITCH + koff]);
        }
#pragma unroll
        for (int mi = 0; mi < 2; ++mi)
#pragma unroll
            for (int nj = 0; nj < 2; ++nj) {
                accy[mi][nj] = __builtin_amdgcn_mfma_f32_16x16x32_bf16(am[mi], bxt[nj], accy[mi][nj], 0, 0, 0);
                accs[mi][nj] = __builtin_amdgcn_mfma_f32_16x16x32_bf16(axt[mi], bbt[nj], accs[mi][nj], 0, 0, 0);
            }
    }

    // ---- stores: Y_intra (bf16, shifted) + S_delta (fp32) ----
    ushort_t* yout = dir ? ybw : yfw;
    float* sd = sdel + ((((size_t)bd * NHEADS_ + h) * 32 + c) * 64) * 64;
#pragma unroll
    for (int mi = 0; mi < 2; ++mi)
#pragma unroll
        for (int nj = 0; nj < 2; ++nj) {
#pragma unroll
            for (int r = 0; r < 4; ++r) {
                int i  = wr * 32 + mi * 16 + rg * 4 + r;   // time (Y) / hd (S)
                int jd = wc * 32 + nj * 16 + fr;           // hd (Y) / ds (S)
                sd[(size_t)i * 64 + jd] = accs[mi][nj][r];
                int tau = c * 64 + i;
                float val = accy[mi][nj][r];
                int tout;
                if (tau == L_SEQ - 1) { tout = dir ? (L_SEQ - 1) : 0; val = 0.f; }
                else                  { tout = dir ? (L_SEQ - 2 - tau) : (tau + 1); }
                yout[((size_t)beta * L_SEQ + tout) * DINNER + h * 64 + jd] = f2bf(val);
            }
        }
}

// ---------------- SSD sequential kernel (K_B): state carry + Y_inter RMW --------------
// grid = (h, bd, half); 256 threads = 4 waves (i-blocks of 16).
// Per chunk: Y_inter = P_i*(C @ S^T) added into yfw/ybw (RMW); S = Ptot*S + S_delta.
__global__ __launch_bounds__(256)
void ssd_seq_kernel(const ushort_t* __restrict__ xBCbf, const float* __restrict__ Pbuf,
                    const float* __restrict__ sdel,
                    ushort_t* __restrict__ yfw, ushort_t* __restrict__ ybw) {
    const int h    = blockIdx.x;
    const int bd   = blockIdx.y;
    const int half = blockIdx.z;
    const int dir = bd >> 1, beta = bd & 1;
    const int tid = threadIdx.x;
    const int wave = tid >> 6, lane = tid & 63;
    const int fr = lane & 15, kg = lane >> 4, rg = lane >> 4;
    const int i0 = wave * 16;

    __shared__ short Cs[64 * PITCH];
    __shared__ float Pl[64];

    // S regs: sreg[nf][s*8+q] = S[half*32 + nf*16 + fr][s*32 + kg*8 + q]
    float sreg[2][16];
#pragma unroll
    for (int nf = 0; nf < 2; ++nf)
#pragma unroll
        for (int q = 0; q < 16; ++q) sreg[nf][q] = 0.f;

    ushort_t* yout = dir ? ybw : yfw;
    const int row = tid >> 2, seg = tid & 3;

    for (int c = 0; c < 32; ++c) {
        {
            const int tau_r = c * 64 + row;
            const int tt = dir ? (L_SEQ - 1 - tau_r) : tau_r;
            const ushort_t* gbase = xBCbf + ((size_t)beta * L_SEQ + tt) * CONVDIM + DINNER + dir * 128 + 64;
            uint4 cv0 = *reinterpret_cast<const uint4*>(gbase + seg * 16);
            uint4 cv1 = *reinterpret_cast<const uint4*>(gbase + seg * 16 + 8);
            *reinterpret_cast<uint4*>(&Cs[row * PITCH + seg * 16])     = cv0;
            *reinterpret_cast<uint4*>(&Cs[row * PITCH + seg * 16 + 8]) = cv1;
            if (tid < 64) Pl[tid] = Pbuf[((size_t)bd * NHEADS_ + h) * L_SEQ + c * 64 + tid];
        }
        __syncthreads();

        // Y_inter = C @ S^T
        f32x4 accy[2];
        accy[0] = (f32x4){0.f, 0.f, 0.f, 0.f};
        accy[1] = (f32x4){0.f, 0.f, 0.f, 0.f};
#pragma unroll
        for (int s = 0; s < 2; ++s) {
            int koff = kg * 8 + s * 32;
            bf16x8 af = *reinterpret_cast<const bf16x8*>(&Cs[(i0 + fr) * PITCH + koff]);
#pragma unroll
            for (int nf = 0; nf < 2; ++nf) {
                bf16x8 bf;
#pragma unroll
                for (int q = 0; q < 8; ++q) bf[q] = (short)f2bf(sreg[nf][s * 8 + q]);
                accy[nf] = __builtin_amdgcn_mfma_f32_16x16x32_bf16(af, bf, accy[nf], 0, 0, 0);
            }
        }

        // RMW: y = Y_intra (already there) + P_i * Y_inter
#pragma unroll
        for (int nf = 0; nf < 2; ++nf) {
            int hdl = half * 32 + nf * 16 + fr;
#pragma unroll
            for (int r = 0; r < 4; ++r) {
                int i = i0 + rg * 4 + r;
                int tau = c * 64 + i;
                int tout;
                bool bound = (tau == L_SEQ - 1);
                tout = bound ? (dir ? (L_SEQ - 1) : 0) : (dir ? (L_SEQ - 2 - tau) : (tau + 1));
                size_t idx = ((size_t)beta * L_SEQ + tout) * DINNER + h * 64 + hdl;
                float val = bound ? 0.f : (accy[nf][r] * Pl[i] + bf2f(yout[idx]));
                yout[idx] = f2bf(val);
            }
        }

        // S = Ptot * S + S_delta
        {
            const float ptot = Pl[63];
            const float* sd = sdel + ((((size_t)bd * NHEADS_ + h) * 32 + c) * 64) * 64;
#pragma unroll
            for (int nf = 0; nf < 2; ++nf) {
                int hdl = half * 32 + nf * 16 + fr;
#pragma unroll
                for (int s = 0; s < 2; ++s) {
                    float4 d0 = *reinterpret_cast<const float4*>(&sd[(size_t)hdl * 64 + s * 32 + kg * 8]);
                    float4 d1 = *reinterpret_cast<const float4*>(&sd[(size_t)hdl * 64 + s * 32 + kg * 8 + 4]);
                    sreg[nf][s * 8 + 0] = ptot * sreg[nf][s * 8 + 0] + d0.x;
                    sreg[nf][s * 8 + 1] = ptot * sreg[nf][s * 8 + 1] + d0.y;
                    sreg[nf][s * 8 + 2] = ptot * sreg[nf][s * 8 + 2] + d0.z;
                    sreg[nf][s * 8 + 3] = ptot * sreg[nf][s * 8 + 3] + d0.w;
                    sreg[nf][s * 8 + 4] = ptot * sreg[nf][s * 8 + 4] + d1.x;
                    sreg[nf][s * 8 + 5] = ptot * sreg[nf][s * 8 + 5] + d1.y;
                    sreg[nf][s * 8 + 6] = ptot * sreg[nf][s * 8 + 6] + d1.z;
                    sreg[nf][s * 8 + 7] = ptot * sreg[nf][s * 8 + 7] + d1.w;
                }
            }
        }
        __syncthreads();
    }
}

// ---------------- diag_heads = x . fc_D_w^T + Dp  (one wave per row) ------------------
__global__ __launch_bounds__(64)
void diag_kernel(const ushort_t* __restrict__ xBCbf, const float* __restrict__ fcD,
                 const float* __restrict__ Dp, float* __restrict__ diag) {
    const int row = blockIdx.x;            // beta*L + t
    const int lane = threadIdx.x;
    const ushort_t* x = xBCbf + (size_t)row * CONVDIM;   // channels 0..2047 = x
    float acc[NHEADS_];
#pragma unroll
    for (int hh = 0; hh < NHEADS_; ++hh) acc[hh] = 0.f;
    for (int k0 = 0; k0 < DINNER; k0 += 64) {
        float xv = bf2f(x[k0 + lane]);
#pragma unroll 8
        for (int hh = 0; hh < NHEADS_; ++hh)
            acc[hh] += xv * fcD[(size_t)hh * DINNER + k0 + lane];
    }
#pragma unroll
    for (int hh = 0; hh < NHEADS_; ++hh) {
        float v = acc[hh];
        v += __shfl_xor(v, 1);  v += __shfl_xor(v, 2);  v += __shfl_xor(v, 4);
        v += __shfl_xor(v, 8);  v += __shfl_xor(v, 16); v += __shfl_xor(v, 32);
        acc[hh] = v;
    }
    float outv = 0.f;
#pragma unroll
    for (int hh = 0; hh < NHEADS_; ++hh)
        if (lane == hh) outv = acc[hh];
    if (lane < NHEADS_) diag[(size_t)row * NHEADS_ + lane] = outv + Dp[lane];
}

// ---------------- combine + RMSNorm + silu(z) gate -> bf16 y ---------------------------
__global__ __launch_bounds__(256)
void combine_rms(const ushort_t* __restrict__ yfw, const ushort_t* __restrict__ ybw,
                 const ushort_t* __restrict__ xBCbf, const float* __restrict__ diag,
                 const ushort_t* __restrict__ zbf, const float* __restrict__ norm_w,
                 ushort_t* __restrict__ ybf) {
    const int row = blockIdx.x;
    const int tid = threadIdx.x;
    union U4 { uint4 v; ushort_t s[8]; };
    U4 yf, yb, xv, zv;
    yf.v = *reinterpret_cast<const uint4*>(yfw + (size_t)row * DINNER + tid * 8);
    yb.v = *reinterpret_cast<const uint4*>(ybw + (size_t)row * DINNER + tid * 8);
    xv.v = *reinterpret_cast<const uint4*>(xBCbf + (size_t)row * CONVDIM + tid * 8);
    zv.v = *reinterpret_cast<const uint4*>(zbf + (size_t)row * DINNER + tid * 8);
    const float dgv = diag[(size_t)row * NHEADS_ + (tid >> 3)];
    float v[8];
    float ss = 0.f;
#pragma unroll
    for (int i = 0; i < 8; ++i) {
        float val = bf2f(yf.s[i]) + bf2f(yb.s[i]) + bf2f(xv.s[i]) * dgv;
        v[i] = val;
        ss += val * val;
    }
    ss += __shfl_xor(ss, 1);  ss += __shfl_xor(ss, 2);  ss += __shfl_xor(ss, 4);
    ss += __shfl_xor(ss, 8);  ss += __shfl_xor(ss, 16); ss += __shfl_xor(ss, 32);
    __shared__ float wsum[4];
    if ((tid & 63) == 0) wsum[tid >> 6] = ss;
    __syncthreads();
    ss = wsum[0] + wsum[1] + wsum[2] + wsum[3];
    const float inv = rsqrtf(ss * (1.f / DINNER) + EPS_);
    U4 outv;
#pragma unroll
    for (int i = 0; i < 8; ++i) {
        int c = tid * 8 + i;
        outv.s[i] = f2bf(norm_w[c] * v[i] * inv * silu_f(bf2f(zv.s[i])));
    }
    *reinterpret_cast<uint4*>(ybf + (size_t)row * DINNER + tid * 8) = outv.v;
}

extern "C" void kernel_launch(void* const* d_in, const int* in_sizes, int n_in,
                              void* d_out, int out_size, void* d_ws, size_t ws_size,
                              hipStream_t stream) {
    const float* u       = (const float*)d_in[0];
    const float* W_in    = (const float*)d_in[1];
    const float* conv_w  = (const float*)d_in[2];
    const float* conv_b  = (const float*)d_in[3];
    const float* dt_bias = (const float*)d_in[4];
    const float* A_log   = (const float*)d_in[5];
    const float* Dp      = (const float*)d_in[6];
    const float* fc_D_w  = (const float*)d_in[7];
    const float* norm_w  = (const float*)d_in[8];
    const float* W_out   = (const float*)d_in[9];
    float* out = (float*)d_out;

    const int ROWS = BATCH_ * L_SEQ;     // 4096
    // ---- workspace layout (~199.6 MB) ----
    float* xdt = (float*)d_ws;                                    // 4096*2368 f32
    ushort_t* zbf   = (ushort_t*)(xdt + (size_t)ROWS * XDT);      // 4096*2048 bf16
    ushort_t* xBCbf = zbf   + (size_t)ROWS * DINNER;              // 4096*2304 bf16
    ushort_t* yfw   = xBCbf + (size_t)ROWS * CONVDIM;             // 4096*2048 bf16
    ushort_t* ybw   = yfw   + (size_t)ROWS * DINNER;              // 4096*2048 bf16
    float* diag  = (float*)(ybw + (size_t)ROWS * DINNER);         // 4096*32 f32
    float* labuf = diag  + (size_t)ROWS * NHEADS_;                // 4*32*2048 f32
    float* Pbuf  = labuf + (size_t)4 * NHEADS_ * L_SEQ;           // 4*32*2048 f32
    float* sdel  = Pbuf  + (size_t)4 * NHEADS_ * L_SEQ;           // 4*32*32*64*64 f32
    ushort_t* wobf = (ushort_t*)(sdel + (size_t)4 * NHEADS_ * 32 * 64 * 64); // 1024*2048
    ushort_t* ubf  = wobf + (size_t)DMODEL * DINNER;              // 4096*1024
    ushort_t* wibf = ubf  + (size_t)ROWS * DMODEL;                // 4480*1024
    ushort_t* ybf  = ubf;   // reuse (ubf+wibf dead after gemm1; 17.6MB >= 16.8MB)

    // 0. dtype conversions
    cvt_bf16<<<(ROWS * DMODEL) / 1024, 256, 0, stream>>>(u, ubf);
    cvt_bf16_pad<<<(DINPROJ_P * DMODEL) / 1024, 256, 0, stream>>>(W_in, wibf);
    cvt_bf16<<<(DMODEL * DINNER) / 1024, 256, 0, stream>>>(W_out, wobf);

    // 1. in_proj GEMM (MFMA, split epilogue): z->zbf (bf16), xBC+dt->xdt (f32)
    dim3 g1(DINPROJ_P / 128, ROWS / 128);
    gemm_nt_mfma<128, 128, 2, 2, 4, 4, 1><<<g1, 256, 0, stream>>>(
        ubf, wibf, nullptr, zbf, xdt, ROWS, DINPROJ_P, DMODEL);

    // 2. depthwise conv + SiLU -> bf16 xBC
    dim3 gc(CONVDIM / 256, L_SEQ / 16, BATCH_);
    conv_kernel<<<gc, 256, 0, stream>>>(xdt, conv_w, conv_b, xBCbf);

    // 2b. log-decay precompute
    dtla_kernel<<<(4 * L_SEQ * NHEADS_) / 256, 256, 0, stream>>>(xdt, dt_bias, A_log, labuf);

    // 3a. SSD chunk-parallel intra work (writes Y_intra into yfw/ybw)
    dim3 ga(32, NHEADS_, 4);
    ssd_chunk_kernel<<<ga, 256, 0, stream>>>(xBCbf, labuf, Pbuf, sdel, yfw, ybw);

    // 3b. SSD sequential state carry; adds Y_inter into yfw/ybw
    dim3 gb(NHEADS_, 4, 2);
    ssd_seq_kernel<<<gb, 256, 0, stream>>>(xBCbf, Pbuf, sdel, yfw, ybw);

    // 4. diag heads
    diag_kernel<<<ROWS, 64, 0, stream>>>(xBCbf, fc_D_w, Dp, diag);

    // 5. combine + RMS norm + gate -> bf16
    combine_rms<<<ROWS, 256, 0, stream>>>(yfw, ybw, xBCbf, diag, zbf, norm_w, ybf);

    // 6. out_proj GEMM (MFMA): out = y @ W_out^T
    dim3 g3(DMODEL / 64, ROWS / 128);
    gemm_nt_mfma<128, 64, 2, 2, 4, 2, 0><<<g3, 256, 0, stream>>>(
        ybf, wobf, out, nullptr, nullptr, ROWS, DMODEL, DINNER);
}

// Round 7
// 478.626 us; speedup vs baseline: 5.9257x; 1.7154x over previous
//
#include <hip/hip_runtime.h>
#include <cstdint>
#include <cstddef>

#define L_SEQ   2048
#define DMODEL  1024
#define DINNER  2048
#define NHEADS_ 32
#define HEADDIM_ 64
#define DSTATE  64
#define CONVDIM 2304
#define DINPROJ 4416
#define DINPROJ_P 4480   // padded to 128-multiple for MFMA tiles
#define XDT     2368     // xBC (2304) + dt (64) fp32 staging width
#define BATCH_  2
#define EPS_    1e-5f
#define PITCH   72       // LDS tile pitch in bf16 elems (144B rows)

typedef __attribute__((ext_vector_type(8))) short bf16x8;
typedef __attribute__((ext_vector_type(4))) float f32x4;
typedef unsigned short ushort_t;
typedef unsigned int uint_t;

__device__ __forceinline__ float silu_f(float v) { return v / (1.f + __expf(-v)); }
__device__ __forceinline__ ushort_t f2bf(float f) {
    uint_t u = __float_as_uint(f);
    return (ushort_t)((u + 0x7FFFu + ((u >> 16) & 1u)) >> 16);   // RNE
}
__device__ __forceinline__ float bf2f(ushort_t u) {
    return __uint_as_float(((uint_t)u) << 16);
}

// ---------------- fp32 -> bf16 conversion (plain) -------------------------------------
__global__ __launch_bounds__(256)
void cvt_bf16(const float* __restrict__ src, ushort_t* __restrict__ dst) {
    const size_t i4 = (size_t)blockIdx.x * 256 + threadIdx.x;
    float4 v = reinterpret_cast<const float4*>(src)[i4];
    ushort_t* d = dst + i4 * 4;
    d[0] = f2bf(v.x); d[1] = f2bf(v.y); d[2] = f2bf(v.z); d[3] = f2bf(v.w);
}

// ---------------- W_in fp32[4416][1024] -> bf16[4480][1024] zero-padded ---------------
__global__ __launch_bounds__(256)
void cvt_bf16_pad(const float* __restrict__ src, ushort_t* __restrict__ dst) {
    const size_t i4 = (size_t)blockIdx.x * 256 + threadIdx.x;   // over 4480*1024/4
    const int row = (int)(i4 / (DMODEL / 4));
    float4 v = make_float4(0.f, 0.f, 0.f, 0.f);
    if (row < DINPROJ) v = reinterpret_cast<const float4*>(src)[i4];
    ushort_t* d = dst + i4 * 4;
    d[0] = f2bf(v.x); d[1] = f2bf(v.y); d[2] = f2bf(v.z); d[3] = f2bf(v.w);
}

// ---------------- fc_D_w fp32[32][2048] -> bf16[64][2048] zero-padded -----------------
__global__ __launch_bounds__(256)
void cvt_fcd(const float* __restrict__ src, ushort_t* __restrict__ dst) {
    const size_t i4 = (size_t)blockIdx.x * 256 + threadIdx.x;   // over 64*2048/4
    const int row = (int)(i4 / (DINNER / 4));
    float4 v = make_float4(0.f, 0.f, 0.f, 0.f);
    if (row < NHEADS_) v = reinterpret_cast<const float4*>(src)[i4];
    ushort_t* d = dst + i4 * 4;
    d[0] = f2bf(v.x); d[1] = f2bf(v.y); d[2] = f2bf(v.z); d[3] = f2bf(v.w);
}

// ---------------- bf16 MFMA GEMM: C = A[M][K] * B[N][K]^T -----------------------------
// MODE 0: plain fp32 C.
// MODE 1: split write (col<2048 -> bf16 zout; 2048..4415 -> fp32 xdt at col-2048,
//         row stride XDT; cols >= 4416 dropped).
// MODE 2: diag epilogue: col<32 -> C[row*32+col] = v + dpv[col].
template<int BM, int BN, int WGM, int WGN, int FM, int FN, int MODE>
__global__ __launch_bounds__(256)
void gemm_nt_mfma(const ushort_t* __restrict__ A, const ushort_t* __restrict__ B,
                  float* __restrict__ C, ushort_t* __restrict__ zout,
                  float* __restrict__ xdt, const float* __restrict__ dpv,
                  int M, int N, int K, int lda, int ldb) {
    __shared__ __align__(16) short As[BM * 32];
    __shared__ __align__(16) short Bs[BN * 32];
    const int tid = threadIdx.x;
    const int wave = tid >> 6, lane = tid & 63;
    const int wr = wave / WGN, wc = wave % WGN;
    const int bm = blockIdx.y * BM, bn = blockIdx.x * BN;
    const int srow = tid >> 2;              // 0..63 staging row per pass
    const int skoff = (tid & 3) * 8;        // bf16 elems along K
    const int fr = lane & 15, kg = lane >> 4;

    f32x4 acc[FM][FN];
#pragma unroll
    for (int m = 0; m < FM; ++m)
#pragma unroll
        for (int n = 0; n < FN; ++n) acc[m][n] = (f32x4){0.f, 0.f, 0.f, 0.f};

    for (int k0 = 0; k0 < K; k0 += 32) {
        uint4 aval[BM / 64], bval[BN / 64];
#pragma unroll
        for (int p = 0; p < BM / 64; ++p)
            aval[p] = *reinterpret_cast<const uint4*>(&A[(size_t)(bm + p * 64 + srow) * lda + k0 + skoff]);
#pragma unroll
        for (int p = 0; p < BN / 64; ++p)
            bval[p] = *reinterpret_cast<const uint4*>(&B[(size_t)(bn + p * 64 + srow) * ldb + k0 + skoff]);
        __syncthreads();
#pragma unroll
        for (int p = 0; p < BM / 64; ++p) {
            int row = p * 64 + srow;
            int byte = (row * 64 + skoff * 2) ^ ((row & 7) << 4);
            *reinterpret_cast<uint4*>(reinterpret_cast<char*>(As) + byte) = aval[p];
        }
#pragma unroll
        for (int p = 0; p < BN / 64; ++p) {
            int row = p * 64 + srow;
            int byte = (row * 64 + skoff * 2) ^ ((row & 7) << 4);
            *reinterpret_cast<uint4*>(reinterpret_cast<char*>(Bs) + byte) = bval[p];
        }
        __syncthreads();

        bf16x8 af[FM], bfv[FN];
#pragma unroll
        for (int m = 0; m < FM; ++m) {
            int row = wr * FM * 16 + m * 16 + fr;
            int byte = (row * 64 + kg * 16) ^ ((row & 7) << 4);
            af[m] = *reinterpret_cast<const bf16x8*>(reinterpret_cast<const char*>(As) + byte);
        }
#pragma unroll
        for (int n = 0; n < FN; ++n) {
            int row = wc * FN * 16 + n * 16 + fr;
            int byte = (row * 64 + kg * 16) ^ ((row & 7) << 4);
            bfv[n] = *reinterpret_cast<const bf16x8*>(reinterpret_cast<const char*>(Bs) + byte);
        }
#pragma unroll
        for (int m = 0; m < FM; ++m)
#pragma unroll
            for (int n = 0; n < FN; ++n)
                acc[m][n] = __builtin_amdgcn_mfma_f32_16x16x32_bf16(af[m], bfv[n], acc[m][n], 0, 0, 0);
    }

    const int rg = lane >> 4;   // C/D: col = lane&15, row = rg*4 + r
#pragma unroll
    for (int m = 0; m < FM; ++m)
#pragma unroll
        for (int n = 0; n < FN; ++n) {
            int col = bn + wc * FN * 16 + n * 16 + fr;
#pragma unroll
            for (int r = 0; r < 4; ++r) {
                int rowg = bm + wr * FM * 16 + m * 16 + rg * 4 + r;
                float v = acc[m][n][r];
                if (MODE == 0) {
                    C[(size_t)rowg * N + col] = v;
                } else if (MODE == 1) {
                    if (col < DINNER)       zout[(size_t)rowg * DINNER + col] = f2bf(v);
                    else if (col < DINPROJ) xdt[(size_t)rowg * XDT + (col - DINNER)] = v;
                } else {
                    if (col < NHEADS_) C[(size_t)rowg * NHEADS_ + col] = v + dpv[col];
                }
            }
        }
}

// ---------------- depthwise conv + bias + SiLU -> bf16 xBC ----------------------------
__global__ __launch_bounds__(256)
void conv_kernel(const float* __restrict__ xdt, const float* __restrict__ conv_w,
                 const float* __restrict__ conv_b, ushort_t* __restrict__ xBCbf) {
    const int c = blockIdx.x * 256 + threadIdx.x;   // channel 0..2303
    const int t0 = blockIdx.y * 16;
    const int beta = blockIdx.z;
    float w[7];
#pragma unroll
    for (int k = 0; k < 7; ++k) w[k] = conv_w[c * 7 + k];
    const float bias = conv_b[c];
    const float* in = xdt + (size_t)beta * L_SEQ * XDT + c;
    float win[7];
#pragma unroll
    for (int j = 0; j < 6; ++j) {
        int t = t0 - 3 + j;
        win[j] = (t >= 0 && t < L_SEQ) ? in[(size_t)t * XDT] : 0.f;
    }
    for (int i = 0; i < 16; ++i) {
        int t = t0 + i;
        int tl = t + 3;
        win[6] = (tl < L_SEQ) ? in[(size_t)tl * XDT] : 0.f;
        float acc = bias;
#pragma unroll
        for (int k = 0; k < 7; ++k) acc += win[k] * w[k];
        xBCbf[((size_t)beta * L_SEQ + t) * CONVDIM + c] = f2bf(silu_f(acc));
#pragma unroll
        for (int j = 0; j < 6; ++j) win[j] = win[j + 1];
    }
}

// ---------------- log-decay precompute: la[bd][h][tau] = A_h * softplus(dt+bias) ------
__global__ __launch_bounds__(256)
void dtla_kernel(const float* __restrict__ xdt, const float* __restrict__ dt_bias,
                 const float* __restrict__ A_log, float* __restrict__ labuf) {
    const int idx = blockIdx.x * 256 + threadIdx.x;     // 4*2048*32
    const int h   = idx & 31;
    const int tau = (idx >> 5) & (L_SEQ - 1);
    const int bd  = idx >> 16;
    const int dir = bd >> 1, beta = bd & 1;
    const int tt  = dir ? (L_SEQ - 1 - tau) : tau;
    const float dtraw = xdt[((size_t)beta * L_SEQ + tt) * XDT + CONVDIM + dir * NHEADS_ + h];
    const float Ah = -__expf(A_log[h]);
    const float dtv = dtraw + dt_bias[h];
    const float sp = (dtv > 15.f) ? dtv : log1pf(__expf(dtv));
    labuf[((size_t)bd * NHEADS_ + h) * L_SEQ + tau] = Ah * sp;
}

// ---------------- SSD chunk kernel (K_A): chunk-parallel intra work --------------------
__global__ __launch_bounds__(256)
void ssd_chunk_kernel(const ushort_t* __restrict__ xBCbf, const float* __restrict__ labuf,
                      float* __restrict__ Pbuf, float* __restrict__ sdel,
                      ushort_t* __restrict__ yfw, ushort_t* __restrict__ ybw) {
    const int c  = blockIdx.x;
    const int h  = blockIdx.y;
    const int bd = blockIdx.z;
    const int dir = bd >> 1, beta = bd & 1;
    const int tid = threadIdx.x;
    const int wave = tid >> 6, lane = tid & 63;
    const int wr = wave >> 1, wc = wave & 1;
    const int fr = lane & 15, kg = lane >> 4, rg = lane >> 4;

    __shared__ short Bs[64 * PITCH], Cs[64 * PITCH], XTs[64 * PITCH],
                     BTs[64 * PITCH], Ms[64 * PITCH];
    __shared__ float lslds[64];

    const int row = tid >> 2, seg = tid & 3;
    const int tau_r = c * 64 + row;
    const int tt = dir ? (L_SEQ - 1 - tau_r) : tau_r;
    const ushort_t* gbase = xBCbf + ((size_t)beta * L_SEQ + tt) * CONVDIM;

    union U4 { uint4 v; ushort_t s[8]; };
    U4 x0, x1, b0, b1, c0, c1;
    x0.v = *reinterpret_cast<const uint4*>(gbase + h * 64 + seg * 16);
    x1.v = *reinterpret_cast<const uint4*>(gbase + h * 64 + seg * 16 + 8);
    b0.v = *reinterpret_cast<const uint4*>(gbase + DINNER + dir * 128 + seg * 16);
    b1.v = *reinterpret_cast<const uint4*>(gbase + DINNER + dir * 128 + seg * 16 + 8);
    c0.v = *reinterpret_cast<const uint4*>(gbase + DINNER + dir * 128 + 64 + seg * 16);
    c1.v = *reinterpret_cast<const uint4*>(gbase + DINNER + dir * 128 + 64 + seg * 16 + 8);

    *reinterpret_cast<uint4*>(&Bs[row * PITCH + seg * 16])     = b0.v;
    *reinterpret_cast<uint4*>(&Bs[row * PITCH + seg * 16 + 8]) = b1.v;
    *reinterpret_cast<uint4*>(&Cs[row * PITCH + seg * 16])     = c0.v;
    *reinterpret_cast<uint4*>(&Cs[row * PITCH + seg * 16 + 8]) = c1.v;
#pragma unroll
    for (int k = 0; k < 8; ++k) {
        XTs[(seg * 16 + k) * PITCH + row]     = x0.s[k];
        XTs[(seg * 16 + 8 + k) * PITCH + row] = x1.s[k];
    }

    if (tid < 64) {
        float v = labuf[((size_t)bd * NHEADS_ + h) * L_SEQ + c * 64 + tid];
#pragma unroll
        for (int d = 1; d < 64; d <<= 1) {
            float t = __shfl_up(v, d);
            if (lane >= d) v += t;
        }
        lslds[tid] = v;
        Pbuf[((size_t)bd * NHEADS_ + h) * L_SEQ + c * 64 + tid] = __expf(v);
    }
    __syncthreads();

    {
        const float wrow = __expf(lslds[63] - lslds[row]);
#pragma unroll
        for (int k = 0; k < 8; ++k) {
            BTs[(seg * 16 + k) * PITCH + row]     = (short)f2bf(bf2f(b0.s[k]) * wrow);
            BTs[(seg * 16 + 8 + k) * PITCH + row] = (short)f2bf(bf2f(b1.s[k]) * wrow);
        }
    }

    // ---- G = C @ B^T ----
    f32x4 accg[2][2];
#pragma unroll
    for (int mi = 0; mi < 2; ++mi)
#pragma unroll
        for (int nj = 0; nj < 2; ++nj) accg[mi][nj] = (f32x4){0.f, 0.f, 0.f, 0.f};
#pragma unroll
    for (int s = 0; s < 2; ++s) {
        int koff = kg * 8 + s * 32;
        bf16x8 af[2], bfv[2];
#pragma unroll
        for (int mi = 0; mi < 2; ++mi)
            af[mi] = *reinterpret_cast<const bf16x8*>(&Cs[(wr * 32 + mi * 16 + fr) * PITCH + koff]);
#pragma unroll
        for (int nj = 0; nj < 2; ++nj)
            bfv[nj] = *reinterpret_cast<const bf16x8*>(&Bs[(wc * 32 + nj * 16 + fr) * PITCH + koff]);
#pragma unroll
        for (int mi = 0; mi < 2; ++mi)
#pragma unroll
            for (int nj = 0; nj < 2; ++nj)
                accg[mi][nj] = __builtin_amdgcn_mfma_f32_16x16x32_bf16(af[mi], bfv[nj], accg[mi][nj], 0, 0, 0);
    }

    // ---- M = mask .* exp(ls_i - ls_j) .* G -> bf16 LDS ----
#pragma unroll
    for (int mi = 0; mi < 2; ++mi)
#pragma unroll
        for (int nj = 0; nj < 2; ++nj) {
            int j = wc * 32 + nj * 16 + fr;
            float lsj = lslds[j];
#pragma unroll
            for (int r = 0; r < 4; ++r) {
                int i = wr * 32 + mi * 16 + rg * 4 + r;
                float v = accg[mi][nj][r];
                v = (i >= j) ? v * __expf(lslds[i] - lsj) : 0.f;
                Ms[i * PITCH + j] = (short)f2bf(v);
            }
        }
    __syncthreads();

    // ---- Y_intra = M @ X ; S_delta = X^T @ Bw ----
    f32x4 accy[2][2], accs[2][2];
#pragma unroll
    for (int mi = 0; mi < 2; ++mi)
#pragma unroll
        for (int nj = 0; nj < 2; ++nj) {
            accy[mi][nj] = (f32x4){0.f, 0.f, 0.f, 0.f};
            accs[mi][nj] = (f32x4){0.f, 0.f, 0.f, 0.f};
        }
#pragma unroll
    for (int s = 0; s < 2; ++s) {
        int koff = kg * 8 + s * 32;
        bf16x8 am[2], axt[2], bxt[2], bbt[2];
#pragma unroll
        for (int mi = 0; mi < 2; ++mi) {
            am[mi]  = *reinterpret_cast<const bf16x8*>(&Ms[(wr * 32 + mi * 16 + fr) * PITCH + koff]);
            axt[mi] = *reinterpret_cast<const bf16x8*>(&XTs[(wr * 32 + mi * 16 + fr) * PITCH + koff]);
        }
#pragma unroll
        for (int nj = 0; nj < 2; ++nj) {
            bxt[nj] = *reinterpret_cast<const bf16x8*>(&XTs[(wc * 32 + nj * 16 + fr) * PITCH + koff]);
            bbt[nj] = *reinterpret_cast<const bf16x8*>(&BTs[(wc * 32 + nj * 16 + fr) * PITCH + koff]);
        }
#pragma unroll
        for (int mi = 0; mi < 2; ++mi)
#pragma unroll
            for (int nj = 0; nj < 2; ++nj) {
                accy[mi][nj] = __builtin_amdgcn_mfma_f32_16x16x32_bf16(am[mi], bxt[nj], accy[mi][nj], 0, 0, 0);
                accs[mi][nj] = __builtin_amdgcn_mfma_f32_16x16x32_bf16(axt[mi], bbt[nj], accs[mi][nj], 0, 0, 0);
            }
    }

    // ---- stores: Y_intra (bf16, shifted) + S_delta (fp32) ----
    ushort_t* yout = dir ? ybw : yfw;
    float* sd = sdel + ((((size_t)bd * NHEADS_ + h) * 32 + c) * 64) * 64;
#pragma unroll
    for (int mi = 0; mi < 2; ++mi)
#pragma unroll
        for (int nj = 0; nj < 2; ++nj) {
#pragma unroll
            for (int r = 0; r < 4; ++r) {
                int i  = wr * 32 + mi * 16 + rg * 4 + r;   // time (Y) / hd (S)
                int jd = wc * 32 + nj * 16 + fr;           // hd (Y) / ds (S)
                sd[(size_t)i * 64 + jd] = accs[mi][nj][r];
                int tau = c * 64 + i;
                float val = accy[mi][nj][r];
                int tout;
                if (tau == L_SEQ - 1) { tout = dir ? (L_SEQ - 1) : 0; val = 0.f; }
                else                  { tout = dir ? (L_SEQ - 2 - tau) : (tau + 1); }
                yout[((size_t)beta * L_SEQ + tout) * DINNER + h * 64 + jd] = f2bf(val);
            }
        }
}

// ---------------- SSD sequential kernel (K_B): state carry + Y_inter RMW --------------
__global__ __launch_bounds__(256)
void ssd_seq_kernel(const ushort_t* __restrict__ xBCbf, const float* __restrict__ Pbuf,
                    const float* __restrict__ sdel,
                    ushort_t* __restrict__ yfw, ushort_t* __restrict__ ybw) {
    const int h    = blockIdx.x;
    const int bd   = blockIdx.y;
    const int half = blockIdx.z;
    const int dir = bd >> 1, beta = bd & 1;
    const int tid = threadIdx.x;
    const int wave = tid >> 6, lane = tid & 63;
    const int fr = lane & 15, kg = lane >> 4, rg = lane >> 4;
    const int i0 = wave * 16;

    __shared__ short Cs[64 * PITCH];
    __shared__ float Pl[64];

    float sreg[2][16];
#pragma unroll
    for (int nf = 0; nf < 2; ++nf)
#pragma unroll
        for (int q = 0; q < 16; ++q) sreg[nf][q] = 0.f;

    ushort_t* yout = dir ? ybw : yfw;
    const int row = tid >> 2, seg = tid & 3;

    for (int c = 0; c < 32; ++c) {
        {
            const int tau_r = c * 64 + row;
            const int tt = dir ? (L_SEQ - 1 - tau_r) : tau_r;
            const ushort_t* gbase = xBCbf + ((size_t)beta * L_SEQ + tt) * CONVDIM + DINNER + dir * 128 + 64;
            uint4 cv0 = *reinterpret_cast<const uint4*>(gbase + seg * 16);
            uint4 cv1 = *reinterpret_cast<const uint4*>(gbase + seg * 16 + 8);
            *reinterpret_cast<uint4*>(&Cs[row * PITCH + seg * 16])     = cv0;
            *reinterpret_cast<uint4*>(&Cs[row * PITCH + seg * 16 + 8]) = cv1;
            if (tid < 64) Pl[tid] = Pbuf[((size_t)bd * NHEADS_ + h) * L_SEQ + c * 64 + tid];
        }
        __syncthreads();

        f32x4 accy[2];
        accy[0] = (f32x4){0.f, 0.f, 0.f, 0.f};
        accy[1] = (f32x4){0.f, 0.f, 0.f, 0.f};
#pragma unroll
        for (int s = 0; s < 2; ++s) {
            int koff = kg * 8 + s * 32;
            bf16x8 af = *reinterpret_cast<const bf16x8*>(&Cs[(i0 + fr) * PITCH + koff]);
#pragma unroll
            for (int nf = 0; nf < 2; ++nf) {
                bf16x8 bf;
#pragma unroll
                for (int q = 0; q < 8; ++q) bf[q] = (short)f2bf(sreg[nf][s * 8 + q]);
                accy[nf] = __builtin_amdgcn_mfma_f32_16x16x32_bf16(af, bf, accy[nf], 0, 0, 0);
            }
        }

#pragma unroll
        for (int nf = 0; nf < 2; ++nf) {
            int hdl = half * 32 + nf * 16 + fr;
#pragma unroll
            for (int r = 0; r < 4; ++r) {
                int i = i0 + rg * 4 + r;
                int tau = c * 64 + i;
                int tout;
                bool bound = (tau == L_SEQ - 1);
                tout = bound ? (dir ? (L_SEQ - 1) : 0) : (dir ? (L_SEQ - 2 - tau) : (tau + 1));
                size_t idx = ((size_t)beta * L_SEQ + tout) * DINNER + h * 64 + hdl;
                float val = bound ? 0.f : (accy[nf][r] * Pl[i] + bf2f(yout[idx]));
                yout[idx] = f2bf(val);
            }
        }

        {
            const float ptot = Pl[63];
            const float* sd = sdel + ((((size_t)bd * NHEADS_ + h) * 32 + c) * 64) * 64;
#pragma unroll
            for (int nf = 0; nf < 2; ++nf) {
                int hdl = half * 32 + nf * 16 + fr;
#pragma unroll
                for (int s = 0; s < 2; ++s) {
                    float4 d0 = *reinterpret_cast<const float4*>(&sd[(size_t)hdl * 64 + s * 32 + kg * 8]);
                    float4 d1 = *reinterpret_cast<const float4*>(&sd[(size_t)hdl * 64 + s * 32 + kg * 8 + 4]);
                    sreg[nf][s * 8 + 0] = ptot * sreg[nf][s * 8 + 0] + d0.x;
                    sreg[nf][s * 8 + 1] = ptot * sreg[nf][s * 8 + 1] + d0.y;
                    sreg[nf][s * 8 + 2] = ptot * sreg[nf][s * 8 + 2] + d0.z;
                    sreg[nf][s * 8 + 3] = ptot * sreg[nf][s * 8 + 3] + d0.w;
                    sreg[nf][s * 8 + 4] = ptot * sreg[nf][s * 8 + 4] + d1.x;
                    sreg[nf][s * 8 + 5] = ptot * sreg[nf][s * 8 + 5] + d1.y;
                    sreg[nf][s * 8 + 6] = ptot * sreg[nf][s * 8 + 6] + d1.z;
                    sreg[nf][s * 8 + 7] = ptot * sreg[nf][s * 8 + 7] + d1.w;
                }
            }
        }
        __syncthreads();
    }
}

// ---------------- combine + RMSNorm + silu(z) gate -> bf16 y ---------------------------
__global__ __launch_bounds__(256)
void combine_rms(const ushort_t* __restrict__ yfw, const ushort_t* __restrict__ ybw,
                 const ushort_t* __restrict__ xBCbf, const float* __restrict__ diag,
                 const ushort_t* __restrict__ zbf, const float* __restrict__ norm_w,
                 ushort_t* __restrict__ ybf) {
    const int row = blockIdx.x;
    const int tid = threadIdx.x;
    union U4 { uint4 v; ushort_t s[8]; };
    U4 yf, yb, xv, zv;
    yf.v = *reinterpret_cast<const uint4*>(yfw + (size_t)row * DINNER + tid * 8);
    yb.v = *reinterpret_cast<const uint4*>(ybw + (size_t)row * DINNER + tid * 8);
    xv.v = *reinterpret_cast<const uint4*>(xBCbf + (size_t)row * CONVDIM + tid * 8);
    zv.v = *reinterpret_cast<const uint4*>(zbf + (size_t)row * DINNER + tid * 8);
    const float dgv = diag[(size_t)row * NHEADS_ + (tid >> 3)];
    float v[8];
    float ss = 0.f;
#pragma unroll
    for (int i = 0; i < 8; ++i) {
        float val = bf2f(yf.s[i]) + bf2f(yb.s[i]) + bf2f(xv.s[i]) * dgv;
        v[i] = val;
        ss += val * val;
    }
    ss += __shfl_xor(ss, 1);  ss += __shfl_xor(ss, 2);  ss += __shfl_xor(ss, 4);
    ss += __shfl_xor(ss, 8);  ss += __shfl_xor(ss, 16); ss += __shfl_xor(ss, 32);
    __shared__ float wsum[4];
    if ((tid & 63) == 0) wsum[tid >> 6] = ss;
    __syncthreads();
    ss = wsum[0] + wsum[1] + wsum[2] + wsum[3];
    const float inv = rsqrtf(ss * (1.f / DINNER) + EPS_);
    U4 outv;
#pragma unroll
    for (int i = 0; i < 8; ++i) {
        int c = tid * 8 + i;
        outv.s[i] = f2bf(norm_w[c] * v[i] * inv * silu_f(bf2f(zv.s[i])));
    }
    *reinterpret_cast<uint4*>(ybf + (size_t)row * DINNER + tid * 8) = outv.v;
}

extern "C" void kernel_launch(void* const* d_in, const int* in_sizes, int n_in,
                              void* d_out, int out_size, void* d_ws, size_t ws_size,
                              hipStream_t stream) {
    const float* u       = (const float*)d_in[0];
    const float* W_in    = (const float*)d_in[1];
    const float* conv_w  = (const float*)d_in[2];
    const float* conv_b  = (const float*)d_in[3];
    const float* dt_bias = (const float*)d_in[4];
    const float* A_log   = (const float*)d_in[5];
    const float* Dp      = (const float*)d_in[6];
    const float* fc_D_w  = (const float*)d_in[7];
    const float* norm_w  = (const float*)d_in[8];
    const float* W_out   = (const float*)d_in[9];
    float* out = (float*)d_out;

    const int ROWS = BATCH_ * L_SEQ;     // 4096
    // ---- workspace layout (~200 MB) ----
    float* xdt = (float*)d_ws;                                    // 4096*2368 f32
    ushort_t* zbf   = (ushort_t*)(xdt + (size_t)ROWS * XDT);      // 4096*2048 bf16
    ushort_t* xBCbf = zbf   + (size_t)ROWS * DINNER;              // 4096*2304 bf16
    ushort_t* yfw   = xBCbf + (size_t)ROWS * CONVDIM;             // 4096*2048 bf16
    ushort_t* ybw   = yfw   + (size_t)ROWS * DINNER;              // 4096*2048 bf16
    float* diag  = (float*)(ybw + (size_t)ROWS * DINNER);         // 4096*32 f32
    float* labuf = diag  + (size_t)ROWS * NHEADS_;                // 4*32*2048 f32
    float* Pbuf  = labuf + (size_t)4 * NHEADS_ * L_SEQ;           // 4*32*2048 f32
    float* sdel  = Pbuf  + (size_t)4 * NHEADS_ * L_SEQ;           // 4*32*32*64*64 f32
    ushort_t* wobf = (ushort_t*)(sdel + (size_t)4 * NHEADS_ * 32 * 64 * 64); // 1024*2048
    ushort_t* fcdbf = wobf + (size_t)DMODEL * DINNER;             // 64*2048 bf16
    ushort_t* ubf  = fcdbf + (size_t)64 * DINNER;                 // 4096*1024
    ushort_t* wibf = ubf  + (size_t)ROWS * DMODEL;                // 4480*1024
    ushort_t* ybf  = ubf;   // reuse (ubf+wibf dead after gemm1)

    // 0. dtype conversions
    cvt_bf16<<<(ROWS * DMODEL) / 1024, 256, 0, stream>>>(u, ubf);
    cvt_bf16_pad<<<(DINPROJ_P * DMODEL) / 1024, 256, 0, stream>>>(W_in, wibf);
    cvt_bf16<<<(DMODEL * DINNER) / 1024, 256, 0, stream>>>(W_out, wobf);
    cvt_fcd<<<(64 * DINNER) / 1024, 256, 0, stream>>>(fc_D_w, fcdbf);

    // 1. in_proj GEMM (MFMA, split epilogue): z->zbf (bf16), xBC+dt->xdt (f32)
    dim3 g1(DINPROJ_P / 128, ROWS / 128);
    gemm_nt_mfma<128, 128, 2, 2, 4, 4, 1><<<g1, 256, 0, stream>>>(
        ubf, wibf, nullptr, zbf, xdt, nullptr, ROWS, DINPROJ_P, DMODEL, DMODEL, DMODEL);

    // 2. depthwise conv + SiLU -> bf16 xBC
    dim3 gc(CONVDIM / 256, L_SEQ / 16, BATCH_);
    conv_kernel<<<gc, 256, 0, stream>>>(xdt, conv_w, conv_b, xBCbf);

    // 2b. log-decay precompute
    dtla_kernel<<<(4 * L_SEQ * NHEADS_) / 256, 256, 0, stream>>>(xdt, dt_bias, A_log, labuf);

    // 3a. SSD chunk-parallel intra work (writes Y_intra into yfw/ybw)
    dim3 ga(32, NHEADS_, 4);
    ssd_chunk_kernel<<<ga, 256, 0, stream>>>(xBCbf, labuf, Pbuf, sdel, yfw, ybw);

    // 3b. SSD sequential state carry; adds Y_inter into yfw/ybw
    dim3 gb(NHEADS_, 4, 2);
    ssd_seq_kernel<<<gb, 256, 0, stream>>>(xBCbf, Pbuf, sdel, yfw, ybw);

    // 4. diag heads as MFMA GEMM: [4096][32] = xBC[4096][2048(Astride2304)] . fcd[64][2048]^T
    dim3 gd(1, ROWS / 64);
    gemm_nt_mfma<64, 64, 2, 2, 2, 2, 2><<<gd, 256, 0, stream>>>(
        xBCbf, fcdbf, diag, nullptr, nullptr, Dp, ROWS, 64, DINNER, CONVDIM, DINNER);

    // 5. combine + RMS norm + gate -> bf16
    combine_rms<<<ROWS, 256, 0, stream>>>(yfw, ybw, xBCbf, diag, zbf, norm_w, ybf);

    // 6. out_proj GEMM (MFMA): out = y @ W_out^T
    dim3 g3(DMODEL / 64, ROWS / 128);
    gemm_nt_mfma<128, 64, 2, 2, 4, 2, 0><<<g3, 256, 0, stream>>>(
        ybf, wobf, out, nullptr, nullptr, nullptr, ROWS, DMODEL, DINNER, DINNER, DINNER);
}

// Round 8
// 468.977 us; speedup vs baseline: 6.0476x; 1.0206x over previous
//
#include <hip/hip_runtime.h>
#include <cstdint>
#include <cstddef>

#define L_SEQ   2048
#define DMODEL  1024
#define DINNER  2048
#define NHEADS_ 32
#define HEADDIM_ 64
#define DSTATE  64
#define CONVDIM 2304
#define DINPROJ 4416
#define DINPROJ_P 4480   // padded to 128-multiple for MFMA tiles
#define BATCH_  2
#define EPS_    1e-5f
#define PITCH   72       // LDS tile pitch in bf16 elems (144B rows)

typedef __attribute__((ext_vector_type(8))) short bf16x8;
typedef __attribute__((ext_vector_type(4))) float f32x4;
typedef unsigned short ushort_t;
typedef unsigned int uint_t;

__device__ __forceinline__ float silu_f(float v) { return v / (1.f + __expf(-v)); }
__device__ __forceinline__ ushort_t f2bf(float f) {
    uint_t u = __float_as_uint(f);
    return (ushort_t)((u + 0x7FFFu + ((u >> 16) & 1u)) >> 16);   // RNE
}
__device__ __forceinline__ float bf2f(ushort_t u) {
    return __uint_as_float(((uint_t)u) << 16);
}

// ---------------- fp32 -> bf16 conversion (plain) -------------------------------------
__global__ __launch_bounds__(256)
void cvt_bf16(const float* __restrict__ src, ushort_t* __restrict__ dst) {
    const size_t i4 = (size_t)blockIdx.x * 256 + threadIdx.x;
    float4 v = reinterpret_cast<const float4*>(src)[i4];
    ushort_t* d = dst + i4 * 4;
    d[0] = f2bf(v.x); d[1] = f2bf(v.y); d[2] = f2bf(v.z); d[3] = f2bf(v.w);
}

// ---------------- W_in fp32[4416][1024] -> bf16[4480][1024] zero-padded ---------------
__global__ __launch_bounds__(256)
void cvt_bf16_pad(const float* __restrict__ src, ushort_t* __restrict__ dst) {
    const size_t i4 = (size_t)blockIdx.x * 256 + threadIdx.x;   // over 4480*1024/4
    const int row = (int)(i4 / (DMODEL / 4));
    float4 v = make_float4(0.f, 0.f, 0.f, 0.f);
    if (row < DINPROJ) v = reinterpret_cast<const float4*>(src)[i4];
    ushort_t* d = dst + i4 * 4;
    d[0] = f2bf(v.x); d[1] = f2bf(v.y); d[2] = f2bf(v.z); d[3] = f2bf(v.w);
}

// ---------------- fc_D_w fp32[32][2048] -> bf16[64][2048] zero-padded -----------------
__global__ __launch_bounds__(256)
void cvt_fcd(const float* __restrict__ src, ushort_t* __restrict__ dst) {
    const size_t i4 = (size_t)blockIdx.x * 256 + threadIdx.x;   // over 64*2048/4
    const int row = (int)(i4 / (DINNER / 4));
    float4 v = make_float4(0.f, 0.f, 0.f, 0.f);
    if (row < NHEADS_) v = reinterpret_cast<const float4*>(src)[i4];
    ushort_t* d = dst + i4 * 4;
    d[0] = f2bf(v.x); d[1] = f2bf(v.y); d[2] = f2bf(v.z); d[3] = f2bf(v.w);
}

// ---------------- bf16 MFMA GEMM: C = A[M][K](lda) * B[N][K](ldb)^T -------------------
// 1D grid with bijective XCD swizzle (m204); m-major block order (each XCD owns
// contiguous bm rows -> A-panel L2-local).
// MODE 0: fp32 C (row stride N). MODE 1: bf16 C (row stride N). MODE 2: diag epilogue.
template<int BM, int BN, int WGM, int WGN, int FM, int FN, int MODE>
__global__ __launch_bounds__(256)
void gemm_nt_mfma(const ushort_t* __restrict__ A, const ushort_t* __restrict__ B,
                  float* __restrict__ C, ushort_t* __restrict__ Cbf,
                  const float* __restrict__ dpv,
                  int M, int N, int K, int lda, int ldb, int nbn) {
    // ---- XCD-bijective block swizzle ----
    const int nwg = gridDim.x;
    const int orig = blockIdx.x;
    const int xcd = orig & 7, q = nwg >> 3, r = nwg & 7;
    const int wg = ((xcd < r) ? (xcd * (q + 1)) : (r * (q + 1) + (xcd - r) * q)) + (orig >> 3);
    const int bm = (wg / nbn) * BM, bn = (wg % nbn) * BN;

    __shared__ __align__(16) short As[BM * 32];
    __shared__ __align__(16) short Bs[BN * 32];
    const int tid = threadIdx.x;
    const int wave = tid >> 6, lane = tid & 63;
    const int wr = wave / WGN, wc = wave % WGN;
    const int srow = tid >> 2;              // 0..63 staging row per pass
    const int skoff = (tid & 3) * 8;        // bf16 elems along K
    const int fr = lane & 15, kg = lane >> 4;

    f32x4 acc[FM][FN];
#pragma unroll
    for (int m = 0; m < FM; ++m)
#pragma unroll
        for (int n = 0; n < FN; ++n) acc[m][n] = (f32x4){0.f, 0.f, 0.f, 0.f};

    for (int k0 = 0; k0 < K; k0 += 32) {
        uint4 aval[BM / 64], bval[BN / 64];
#pragma unroll
        for (int p = 0; p < BM / 64; ++p)
            aval[p] = *reinterpret_cast<const uint4*>(&A[(size_t)(bm + p * 64 + srow) * lda + k0 + skoff]);
#pragma unroll
        for (int p = 0; p < BN / 64; ++p)
            bval[p] = *reinterpret_cast<const uint4*>(&B[(size_t)(bn + p * 64 + srow) * ldb + k0 + skoff]);
        __syncthreads();
#pragma unroll
        for (int p = 0; p < BM / 64; ++p) {
            int row = p * 64 + srow;
            int byte = (row * 64 + skoff * 2) ^ ((row & 7) << 4);
            *reinterpret_cast<uint4*>(reinterpret_cast<char*>(As) + byte) = aval[p];
        }
#pragma unroll
        for (int p = 0; p < BN / 64; ++p) {
            int row = p * 64 + srow;
            int byte = (row * 64 + skoff * 2) ^ ((row & 7) << 4);
            *reinterpret_cast<uint4*>(reinterpret_cast<char*>(Bs) + byte) = bval[p];
        }
        __syncthreads();

        bf16x8 af[FM], bfv[FN];
#pragma unroll
        for (int m = 0; m < FM; ++m) {
            int row = wr * FM * 16 + m * 16 + fr;
            int byte = (row * 64 + kg * 16) ^ ((row & 7) << 4);
            af[m] = *reinterpret_cast<const bf16x8*>(reinterpret_cast<const char*>(As) + byte);
        }
#pragma unroll
        for (int n = 0; n < FN; ++n) {
            int row = wc * FN * 16 + n * 16 + fr;
            int byte = (row * 64 + kg * 16) ^ ((row & 7) << 4);
            bfv[n] = *reinterpret_cast<const bf16x8*>(reinterpret_cast<const char*>(Bs) + byte);
        }
#pragma unroll
        for (int m = 0; m < FM; ++m)
#pragma unroll
            for (int n = 0; n < FN; ++n)
                acc[m][n] = __builtin_amdgcn_mfma_f32_16x16x32_bf16(af[m], bfv[n], acc[m][n], 0, 0, 0);
    }

    const int rg = lane >> 4;   // C/D: col = lane&15, row = rg*4 + r
#pragma unroll
    for (int m = 0; m < FM; ++m)
#pragma unroll
        for (int n = 0; n < FN; ++n) {
            int col = bn + wc * FN * 16 + n * 16 + fr;
#pragma unroll
            for (int r = 0; r < 4; ++r) {
                int rowg = bm + wr * FM * 16 + m * 16 + rg * 4 + r;
                float v = acc[m][n][r];
                if (MODE == 0) {
                    C[(size_t)rowg * N + col] = v;
                } else if (MODE == 1) {
                    Cbf[(size_t)rowg * N + col] = f2bf(v);
                } else {
                    if (col < NHEADS_) C[(size_t)rowg * NHEADS_ + col] = v + dpv[col];
                }
            }
        }
}

// ---------------- depthwise conv + bias + SiLU -> bf16 xBC ----------------------------
__global__ __launch_bounds__(256)
void conv_kernel(const ushort_t* __restrict__ zxbf, const float* __restrict__ conv_w,
                 const float* __restrict__ conv_b, ushort_t* __restrict__ xBCbf) {
    const int c = blockIdx.x * 256 + threadIdx.x;   // channel 0..2303
    const int t0 = blockIdx.y * 16;
    const int beta = blockIdx.z;
    float w[7];
#pragma unroll
    for (int k = 0; k < 7; ++k) w[k] = conv_w[c * 7 + k];
    const float bias = conv_b[c];
    const ushort_t* in = zxbf + (size_t)beta * L_SEQ * DINPROJ_P + DINNER + c;
    float win[7];
#pragma unroll
    for (int j = 0; j < 6; ++j) {
        int t = t0 - 3 + j;
        win[j] = (t >= 0 && t < L_SEQ) ? bf2f(in[(size_t)t * DINPROJ_P]) : 0.f;
    }
    for (int i = 0; i < 16; ++i) {
        int t = t0 + i;
        int tl = t + 3;
        win[6] = (tl < L_SEQ) ? bf2f(in[(size_t)tl * DINPROJ_P]) : 0.f;
        float acc = bias;
#pragma unroll
        for (int k = 0; k < 7; ++k) acc += win[k] * w[k];
        xBCbf[((size_t)beta * L_SEQ + t) * CONVDIM + c] = f2bf(silu_f(acc));
#pragma unroll
        for (int j = 0; j < 6; ++j) win[j] = win[j + 1];
    }
}

// ---------------- log-decay precompute: la[bd][h][tau] = A_h * softplus(dt+bias) ------
__global__ __launch_bounds__(256)
void dtla_kernel(const ushort_t* __restrict__ zxbf, const float* __restrict__ dt_bias,
                 const float* __restrict__ A_log, float* __restrict__ labuf) {
    const int idx = blockIdx.x * 256 + threadIdx.x;     // 4*2048*32
    const int h   = idx & 31;
    const int tau = (idx >> 5) & (L_SEQ - 1);
    const int bd  = idx >> 16;
    const int dir = bd >> 1, beta = bd & 1;
    const int tt  = dir ? (L_SEQ - 1 - tau) : tau;
    const float dtraw = bf2f(zxbf[((size_t)beta * L_SEQ + tt) * DINPROJ_P + DINNER + CONVDIM + dir * NHEADS_ + h]);
    const float Ah = -__expf(A_log[h]);
    const float dtv = dtraw + dt_bias[h];
    const float sp = (dtv > 15.f) ? dtv : log1pf(__expf(dtv));
    labuf[((size_t)bd * NHEADS_ + h) * L_SEQ + tau] = Ah * sp;
}

// ---------------- SSD chunk kernel (K_A): chunk-parallel intra work --------------------
__global__ __launch_bounds__(256)
void ssd_chunk_kernel(const ushort_t* __restrict__ xBCbf, const float* __restrict__ labuf,
                      float* __restrict__ Pbuf, float* __restrict__ sdel,
                      ushort_t* __restrict__ yfw, ushort_t* __restrict__ ybw) {
    const int c  = blockIdx.x;
    const int h  = blockIdx.y;
    const int bd = blockIdx.z;
    const int dir = bd >> 1, beta = bd & 1;
    const int tid = threadIdx.x;
    const int wave = tid >> 6, lane = tid & 63;
    const int wr = wave >> 1, wc = wave & 1;
    const int fr = lane & 15, kg = lane >> 4, rg = lane >> 4;

    __shared__ short Bs[64 * PITCH], Cs[64 * PITCH], XTs[64 * PITCH],
                     BTs[64 * PITCH], Ms[64 * PITCH];
    __shared__ float lslds[64];

    const int row = tid >> 2, seg = tid & 3;
    const int tau_r = c * 64 + row;
    const int tt = dir ? (L_SEQ - 1 - tau_r) : tau_r;
    const ushort_t* gbase = xBCbf + ((size_t)beta * L_SEQ + tt) * CONVDIM;

    union U4 { uint4 v; ushort_t s[8]; };
    U4 x0, x1, b0, b1, c0, c1;
    x0.v = *reinterpret_cast<const uint4*>(gbase + h * 64 + seg * 16);
    x1.v = *reinterpret_cast<const uint4*>(gbase + h * 64 + seg * 16 + 8);
    b0.v = *reinterpret_cast<const uint4*>(gbase + DINNER + dir * 128 + seg * 16);
    b1.v = *reinterpret_cast<const uint4*>(gbase + DINNER + dir * 128 + seg * 16 + 8);
    c0.v = *reinterpret_cast<const uint4*>(gbase + DINNER + dir * 128 + 64 + seg * 16);
    c1.v = *reinterpret_cast<const uint4*>(gbase + DINNER + dir * 128 + 64 + seg * 16 + 8);

    *reinterpret_cast<uint4*>(&Bs[row * PITCH + seg * 16])     = b0.v;
    *reinterpret_cast<uint4*>(&Bs[row * PITCH + seg * 16 + 8]) = b1.v;
    *reinterpret_cast<uint4*>(&Cs[row * PITCH + seg * 16])     = c0.v;
    *reinterpret_cast<uint4*>(&Cs[row * PITCH + seg * 16 + 8]) = c1.v;
#pragma unroll
    for (int k = 0; k < 8; ++k) {
        XTs[(seg * 16 + k) * PITCH + row]     = x0.s[k];
        XTs[(seg * 16 + 8 + k) * PITCH + row] = x1.s[k];
    }

    if (tid < 64) {
        float v = labuf[((size_t)bd * NHEADS_ + h) * L_SEQ + c * 64 + tid];
#pragma unroll
        for (int d = 1; d < 64; d <<= 1) {
            float t = __shfl_up(v, d);
            if (lane >= d) v += t;
        }
        lslds[tid] = v;
        Pbuf[((size_t)bd * NHEADS_ + h) * L_SEQ + c * 64 + tid] = __expf(v);
    }
    __syncthreads();

    {
        const float wrow = __expf(lslds[63] - lslds[row]);
#pragma unroll
        for (int k = 0; k < 8; ++k) {
            BTs[(seg * 16 + k) * PITCH + row]     = (short)f2bf(bf2f(b0.s[k]) * wrow);
            BTs[(seg * 16 + 8 + k) * PITCH + row] = (short)f2bf(bf2f(b1.s[k]) * wrow);
        }
    }

    // ---- G = C @ B^T ----
    f32x4 accg[2][2];
#pragma unroll
    for (int mi = 0; mi < 2; ++mi)
#pragma unroll
        for (int nj = 0; nj < 2; ++nj) accg[mi][nj] = (f32x4){0.f, 0.f, 0.f, 0.f};
#pragma unroll
    for (int s = 0; s < 2; ++s) {
        int koff = kg * 8 + s * 32;
        bf16x8 af[2], bfv[2];
#pragma unroll
        for (int mi = 0; mi < 2; ++mi)
            af[mi] = *reinterpret_cast<const bf16x8*>(&Cs[(wr * 32 + mi * 16 + fr) * PITCH + koff]);
#pragma unroll
        for (int nj = 0; nj < 2; ++nj)
            bfv[nj] = *reinterpret_cast<const bf16x8*>(&Bs[(wc * 32 + nj * 16 + fr) * PITCH + koff]);
#pragma unroll
        for (int mi = 0; mi < 2; ++mi)
#pragma unroll
            for (int nj = 0; nj < 2; ++nj)
                accg[mi][nj] = __builtin_amdgcn_mfma_f32_16x16x32_bf16(af[mi], bfv[nj], accg[mi][nj], 0, 0, 0);
    }

    // ---- M = mask .* exp(ls_i - ls_j) .* G -> bf16 LDS ----
#pragma unroll
    for (int mi = 0; mi < 2; ++mi)
#pragma unroll
        for (int nj = 0; nj < 2; ++nj) {
            int j = wc * 32 + nj * 16 + fr;
            float lsj = lslds[j];
#pragma unroll
            for (int r = 0; r < 4; ++r) {
                int i = wr * 32 + mi * 16 + rg * 4 + r;
                float v = accg[mi][nj][r];
                v = (i >= j) ? v * __expf(lslds[i] - lsj) : 0.f;
                Ms[i * PITCH + j] = (short)f2bf(v);
            }
        }
    __syncthreads();

    // ---- Y_intra = M @ X ; S_delta = X^T @ Bw ----
    f32x4 accy[2][2], accs[2][2];
#pragma unroll
    for (int mi = 0; mi < 2; ++mi)
#pragma unroll
        for (int nj = 0; nj < 2; ++nj) {
            accy[mi][nj] = (f32x4){0.f, 0.f, 0.f, 0.f};
            accs[mi][nj] = (f32x4){0.f, 0.f, 0.f, 0.f};
        }
#pragma unroll
    for (int s = 0; s < 2; ++s) {
        int koff = kg * 8 + s * 32;
        bf16x8 am[2], axt[2], bxt[2], bbt[2];
#pragma unroll
        for (int mi = 0; mi < 2; ++mi) {
            am[mi]  = *reinterpret_cast<const bf16x8*>(&Ms[(wr * 32 + mi * 16 + fr) * PITCH + koff]);
            axt[mi] = *reinterpret_cast<const bf16x8*>(&XTs[(wr * 32 + mi * 16 + fr) * PITCH + koff]);
        }
#pragma unroll
        for (int nj = 0; nj < 2; ++nj) {
            bxt[nj] = *reinterpret_cast<const bf16x8*>(&XTs[(wc * 32 + nj * 16 + fr) * PITCH + koff]);
            bbt[nj] = *reinterpret_cast<const bf16x8*>(&BTs[(wc * 32 + nj * 16 + fr) * PITCH + koff]);
        }
#pragma unroll
        for (int mi = 0; mi < 2; ++mi)
#pragma unroll
            for (int nj = 0; nj < 2; ++nj) {
                accy[mi][nj] = __builtin_amdgcn_mfma_f32_16x16x32_bf16(am[mi], bxt[nj], accy[mi][nj], 0, 0, 0);
                accs[mi][nj] = __builtin_amdgcn_mfma_f32_16x16x32_bf16(axt[mi], bbt[nj], accs[mi][nj], 0, 0, 0);
            }
    }

    // ---- stores: Y_intra (bf16, shifted) + S_delta (fp32) ----
    ushort_t* yout = dir ? ybw : yfw;
    float* sd = sdel + ((((size_t)bd * NHEADS_ + h) * 32 + c) * 64) * 64;
#pragma unroll
    for (int mi = 0; mi < 2; ++mi)
#pragma unroll
        for (int nj = 0; nj < 2; ++nj) {
#pragma unroll
            for (int r = 0; r < 4; ++r) {
                int i  = wr * 32 + mi * 16 + rg * 4 + r;   // time (Y) / hd (S)
                int jd = wc * 32 + nj * 16 + fr;           // hd (Y) / ds (S)
                sd[(size_t)i * 64 + jd] = accs[mi][nj][r];
                int tau = c * 64 + i;
                float val = accy[mi][nj][r];
                int tout;
                if (tau == L_SEQ - 1) { tout = dir ? (L_SEQ - 1) : 0; val = 0.f; }
                else                  { tout = dir ? (L_SEQ - 2 - tau) : (tau + 1); }
                yout[((size_t)beta * L_SEQ + tout) * DINNER + h * 64 + jd] = f2bf(val);
            }
        }
}

// ---------------- SSD sequential kernel (K_B): state carry + Y_inter RMW --------------
__global__ __launch_bounds__(256)
void ssd_seq_kernel(const ushort_t* __restrict__ xBCbf, const float* __restrict__ Pbuf,
                    const float* __restrict__ sdel,
                    ushort_t* __restrict__ yfw, ushort_t* __restrict__ ybw) {
    const int h    = blockIdx.x;
    const int bd   = blockIdx.y;
    const int half = blockIdx.z;
    const int dir = bd >> 1, beta = bd & 1;
    const int tid = threadIdx.x;
    const int wave = tid >> 6, lane = tid & 63;
    const int fr = lane & 15, kg = lane >> 4, rg = lane >> 4;
    const int i0 = wave * 16;

    __shared__ short Cs[64 * PITCH];
    __shared__ float Pl[64];

    float sreg[2][16];
#pragma unroll
    for (int nf = 0; nf < 2; ++nf)
#pragma unroll
        for (int q = 0; q < 16; ++q) sreg[nf][q] = 0.f;

    ushort_t* yout = dir ? ybw : yfw;
    const int row = tid >> 2, seg = tid & 3;

    for (int c = 0; c < 32; ++c) {
        {
            const int tau_r = c * 64 + row;
            const int tt = dir ? (L_SEQ - 1 - tau_r) : tau_r;
            const ushort_t* gbase = xBCbf + ((size_t)beta * L_SEQ + tt) * CONVDIM + DINNER + dir * 128 + 64;
            uint4 cv0 = *reinterpret_cast<const uint4*>(gbase + seg * 16);
            uint4 cv1 = *reinterpret_cast<const uint4*>(gbase + seg * 16 + 8);
            *reinterpret_cast<uint4*>(&Cs[row * PITCH + seg * 16])     = cv0;
            *reinterpret_cast<uint4*>(&Cs[row * PITCH + seg * 16 + 8]) = cv1;
            if (tid < 64) Pl[tid] = Pbuf[((size_t)bd * NHEADS_ + h) * L_SEQ + c * 64 + tid];
        }
        __syncthreads();

        f32x4 accy[2];
        accy[0] = (f32x4){0.f, 0.f, 0.f, 0.f};
        accy[1] = (f32x4){0.f, 0.f, 0.f, 0.f};
#pragma unroll
        for (int s = 0; s < 2; ++s) {
            int koff = kg * 8 + s * 32;
            bf16x8 af = *reinterpret_cast<const bf16x8*>(&Cs[(i0 + fr) * PITCH + koff]);
#pragma unroll
            for (int nf = 0; nf < 2; ++nf) {
                bf16x8 bf;
#pragma unroll
                for (int q = 0; q < 8; ++q) bf[q] = (short)f2bf(sreg[nf][s * 8 + q]);
                accy[nf] = __builtin_amdgcn_mfma_f32_16x16x32_bf16(af, bf, accy[nf], 0, 0, 0);
            }
        }

#pragma unroll
        for (int nf = 0; nf < 2; ++nf) {
            int hdl = half * 32 + nf * 16 + fr;
#pragma unroll
            for (int r = 0; r < 4; ++r) {
                int i = i0 + rg * 4 + r;
                int tau = c * 64 + i;
                int tout;
                bool bound = (tau == L_SEQ - 1);
                tout = bound ? (dir ? (L_SEQ - 1) : 0) : (dir ? (L_SEQ - 2 - tau) : (tau + 1));
                size_t idx = ((size_t)beta * L_SEQ + tout) * DINNER + h * 64 + hdl;
                float val = bound ? 0.f : (accy[nf][r] * Pl[i] + bf2f(yout[idx]));
                yout[idx] = f2bf(val);
            }
        }

        {
            const float ptot = Pl[63];
            const float* sd = sdel + ((((size_t)bd * NHEADS_ + h) * 32 + c) * 64) * 64;
#pragma unroll
            for (int nf = 0; nf < 2; ++nf) {
                int hdl = half * 32 + nf * 16 + fr;
#pragma unroll
                for (int s = 0; s < 2; ++s) {
                    float4 d0 = *reinterpret_cast<const float4*>(&sd[(size_t)hdl * 64 + s * 32 + kg * 8]);
                    float4 d1 = *reinterpret_cast<const float4*>(&sd[(size_t)hdl * 64 + s * 32 + kg * 8 + 4]);
                    sreg[nf][s * 8 + 0] = ptot * sreg[nf][s * 8 + 0] + d0.x;
                    sreg[nf][s * 8 + 1] = ptot * sreg[nf][s * 8 + 1] + d0.y;
                    sreg[nf][s * 8 + 2] = ptot * sreg[nf][s * 8 + 2] + d0.z;
                    sreg[nf][s * 8 + 3] = ptot * sreg[nf][s * 8 + 3] + d0.w;
                    sreg[nf][s * 8 + 4] = ptot * sreg[nf][s * 8 + 4] + d1.x;
                    sreg[nf][s * 8 + 5] = ptot * sreg[nf][s * 8 + 5] + d1.y;
                    sreg[nf][s * 8 + 6] = ptot * sreg[nf][s * 8 + 6] + d1.z;
                    sreg[nf][s * 8 + 7] = ptot * sreg[nf][s * 8 + 7] + d1.w;
                }
            }
        }
        __syncthreads();
    }
}

// ---------------- combine + RMSNorm + silu(z) gate -> bf16 y ---------------------------
__global__ __launch_bounds__(256)
void combine_rms(const ushort_t* __restrict__ yfw, const ushort_t* __restrict__ ybw,
                 const ushort_t* __restrict__ xBCbf, const float* __restrict__ diag,
                 const ushort_t* __restrict__ zxbf, const float* __restrict__ norm_w,
                 ushort_t* __restrict__ ybf) {
    const int row = blockIdx.x;
    const int tid = threadIdx.x;
    union U4 { uint4 v; ushort_t s[8]; };
    U4 yf, yb, xv, zv;
    yf.v = *reinterpret_cast<const uint4*>(yfw + (size_t)row * DINNER + tid * 8);
    yb.v = *reinterpret_cast<const uint4*>(ybw + (size_t)row * DINNER + tid * 8);
    xv.v = *reinterpret_cast<const uint4*>(xBCbf + (size_t)row * CONVDIM + tid * 8);
    zv.v = *reinterpret_cast<const uint4*>(zxbf + (size_t)row * DINPROJ_P + tid * 8);
    const float dgv = diag[(size_t)row * NHEADS_ + (tid >> 3)];
    float v[8];
    float ss = 0.f;
#pragma unroll
    for (int i = 0; i < 8; ++i) {
        float val = bf2f(yf.s[i]) + bf2f(yb.s[i]) + bf2f(xv.s[i]) * dgv;
        v[i] = val;
        ss += val * val;
    }
    ss += __shfl_xor(ss, 1);  ss += __shfl_xor(ss, 2);  ss += __shfl_xor(ss, 4);
    ss += __shfl_xor(ss, 8);  ss += __shfl_xor(ss, 16); ss += __shfl_xor(ss, 32);
    __shared__ float wsum[4];
    if ((tid & 63) == 0) wsum[tid >> 6] = ss;
    __syncthreads();
    ss = wsum[0] + wsum[1] + wsum[2] + wsum[3];
    const float inv = rsqrtf(ss * (1.f / DINNER) + EPS_);
    U4 outv;
#pragma unroll
    for (int i = 0; i < 8; ++i) {
        int c = tid * 8 + i;
        outv.s[i] = f2bf(norm_w[c] * v[i] * inv * silu_f(bf2f(zv.s[i])));
    }
    *reinterpret_cast<uint4*>(ybf + (size_t)row * DINNER + tid * 8) = outv.v;
}

extern "C" void kernel_launch(void* const* d_in, const int* in_sizes, int n_in,
                              void* d_out, int out_size, void* d_ws, size_t ws_size,
                              hipStream_t stream) {
    const float* u       = (const float*)d_in[0];
    const float* W_in    = (const float*)d_in[1];
    const float* conv_w  = (const float*)d_in[2];
    const float* conv_b  = (const float*)d_in[3];
    const float* dt_bias = (const float*)d_in[4];
    const float* A_log   = (const float*)d_in[5];
    const float* Dp      = (const float*)d_in[6];
    const float* fc_D_w  = (const float*)d_in[7];
    const float* norm_w  = (const float*)d_in[8];
    const float* W_out   = (const float*)d_in[9];
    float* out = (float*)d_out;

    const int ROWS = BATCH_ * L_SEQ;     // 4096
    // ---- workspace layout (~181 MB) ----
    ushort_t* zxbf  = (ushort_t*)d_ws;                            // 4096*4480 bf16
    ushort_t* xBCbf = zxbf  + (size_t)ROWS * DINPROJ_P;           // 4096*2304 bf16
    ushort_t* yfw   = xBCbf + (size_t)ROWS * CONVDIM;             // 4096*2048 bf16
    ushort_t* ybw   = yfw   + (size_t)ROWS * DINNER;              // 4096*2048 bf16
    float* diag  = (float*)(ybw + (size_t)ROWS * DINNER);         // 4096*32 f32
    float* labuf = diag  + (size_t)ROWS * NHEADS_;                // 4*32*2048 f32
    float* Pbuf  = labuf + (size_t)4 * NHEADS_ * L_SEQ;           // 4*32*2048 f32
    float* sdel  = Pbuf  + (size_t)4 * NHEADS_ * L_SEQ;           // 4*32*32*64*64 f32
    ushort_t* wobf = (ushort_t*)(sdel + (size_t)4 * NHEADS_ * 32 * 64 * 64); // 1024*2048
    ushort_t* fcdbf = wobf + (size_t)DMODEL * DINNER;             // 64*2048 bf16
    ushort_t* ubf  = fcdbf + (size_t)64 * DINNER;                 // 4096*1024
    ushort_t* wibf = ubf  + (size_t)ROWS * DMODEL;                // 4480*1024
    ushort_t* ybf  = ubf;   // reuse (ubf+wibf dead after gemm1)

    // 0. dtype conversions
    cvt_bf16<<<(ROWS * DMODEL) / 1024, 256, 0, stream>>>(u, ubf);
    cvt_bf16_pad<<<(DINPROJ_P * DMODEL) / 1024, 256, 0, stream>>>(W_in, wibf);
    cvt_bf16<<<(DMODEL * DINNER) / 1024, 256, 0, stream>>>(W_out, wobf);
    cvt_fcd<<<(64 * DINNER) / 1024, 256, 0, stream>>>(fc_D_w, fcdbf);

    // 1. in_proj GEMM (MFMA): zxbf = u @ W_in^T  (bf16 out, single stream, XCD swizzle)
    gemm_nt_mfma<128, 128, 2, 2, 4, 4, 1><<<(ROWS / 128) * (DINPROJ_P / 128), 256, 0, stream>>>(
        ubf, wibf, nullptr, zxbf, nullptr, ROWS, DINPROJ_P, DMODEL, DMODEL, DMODEL, DINPROJ_P / 128);

    // 2. depthwise conv + SiLU -> bf16 xBC
    dim3 gc(CONVDIM / 256, L_SEQ / 16, BATCH_);
    conv_kernel<<<gc, 256, 0, stream>>>(zxbf, conv_w, conv_b, xBCbf);

    // 2b. log-decay precompute
    dtla_kernel<<<(4 * L_SEQ * NHEADS_) / 256, 256, 0, stream>>>(zxbf, dt_bias, A_log, labuf);

    // 3a. SSD chunk-parallel intra work (writes Y_intra into yfw/ybw)
    dim3 ga(32, NHEADS_, 4);
    ssd_chunk_kernel<<<ga, 256, 0, stream>>>(xBCbf, labuf, Pbuf, sdel, yfw, ybw);

    // 3b. SSD sequential state carry; adds Y_inter into yfw/ybw
    dim3 gb(NHEADS_, 4, 2);
    ssd_seq_kernel<<<gb, 256, 0, stream>>>(xBCbf, Pbuf, sdel, yfw, ybw);

    // 4. diag heads as MFMA GEMM: [4096][32] = xBC[4096][2048(lda2304)] . fcd[64][2048]^T
    gemm_nt_mfma<64, 64, 2, 2, 2, 2, 2><<<ROWS / 64, 256, 0, stream>>>(
        xBCbf, fcdbf, diag, nullptr, Dp, ROWS, 64, DINNER, CONVDIM, DINNER, 1);

    // 5. combine + RMS norm + gate -> bf16
    combine_rms<<<ROWS, 256, 0, stream>>>(yfw, ybw, xBCbf, diag, zxbf, norm_w, ybf);

    // 6. out_proj GEMM (MFMA): out = y @ W_out^T (fp32 out, XCD swizzle)
    gemm_nt_mfma<128, 64, 2, 2, 4, 2, 0><<<(ROWS / 128) * (DMODEL / 64), 256, 0, stream>>>(
        ybf, wobf, out, nullptr, nullptr, ROWS, DMODEL, DINNER, DINNER, DINNER, DMODEL / 64);
}